// Round 3
// baseline (1613.861 us; speedup 1.0000x reference)
//
#include <hip/hip_runtime.h>
#include <hip/hip_bf16.h>
#include <math.h>

// ---------------------------------------------------------------------------
// GNN model on MI355X. N=100000, E=1600000, IN_F=16, H_F=256, C=16.
//   CSR build -> k_init/k_agg16 -> k_l1 (fused skip+layer1, bf16 out1)
//   -> k_m2 (bf16 mean) -> emb GEMM (bf16 A, K=512, emb kept in d_out aux
//   region) -> scores/primary + attn heads -> aux branch last (overwrites
//   emb region with the real aux output).
// Workspace budget ~130 MB (round-1 failure was ws overflow at ~476 MB:
// guard returned early, output stayed zero -> absmax 0.52 == max|ref|).
// ---------------------------------------------------------------------------

#define SCANB 1024

__device__ __forceinline__ float sigmoidf_(float x) { return 1.0f / (1.0f + expf(-x)); }

__device__ __forceinline__ float bf2f(unsigned short u) {
    union { unsigned int i; float f; } c;
    c.i = ((unsigned int)u) << 16;
    return c.f;
}
__device__ __forceinline__ unsigned short f2bf(float f) {
    union { float f; unsigned int i; } c;
    c.f = f;
    unsigned int x = c.i;
    x += 0x7fffu + ((x >> 16) & 1u);  // round-to-nearest-even
    return (unsigned short)(x >> 16);
}

// softmax over the 16-element criteria weight vector.
__global__ void k_cw(const float* __restrict__ rw, float* __restrict__ cw, int c) {
    if (threadIdx.x == 0 && blockIdx.x == 0) {
        float mx = -1e30f;
        for (int i = 0; i < c; ++i) mx = fmaxf(mx, rw[i]);
        float s = 0.f;
        for (int i = 0; i < c; ++i) s += expf(rw[i] - mx);
        for (int i = 0; i < c; ++i) cw[i] = expf(rw[i] - mx) / s;
    }
}

__global__ void k_hist(const int* __restrict__ src, const int* __restrict__ dst,
                       int* __restrict__ deg_in, int* __restrict__ deg_out, int e) {
    int i = blockIdx.x * blockDim.x + threadIdx.x;
    if (i < e) {
        atomicAdd(&deg_in[dst[i]], 1);
        atomicAdd(&deg_out[src[i]], 1);
    }
}

// Block-local exclusive scan of deg (SCANB elems / 256-thread block).
__global__ void k_scan1(const int* __restrict__ deg, int* __restrict__ local,
                        int* __restrict__ part, int n) {
    __shared__ int sb[256];
    const int tid = threadIdx.x;
    const int i0 = blockIdx.x * SCANB + tid * 4;
    int v[4];
#pragma unroll
    for (int j = 0; j < 4; ++j) v[j] = (i0 + j < n) ? deg[i0 + j] : 0;
    int t = v[0] + v[1] + v[2] + v[3];
    sb[tid] = t;
    __syncthreads();
    for (int off = 1; off < 256; off <<= 1) {
        int x = sb[tid];
        if (tid >= off) x += sb[tid - off];
        __syncthreads();
        sb[tid] = x;
        __syncthreads();
    }
    int incl = sb[tid];
    int ex = incl - t;
    if (tid == 255) part[blockIdx.x] = incl;
    int p = ex;
#pragma unroll
    for (int j = 0; j < 4; ++j) {
        if (i0 + j < n) local[i0 + j] = p;
        p += v[j];
    }
}

__global__ void k_scan2(int* __restrict__ part, int nb) {
    __shared__ int sb[256];
    const int tid = threadIdx.x;
    int t = (tid < nb) ? part[tid] : 0;
    sb[tid] = t;
    __syncthreads();
    for (int off = 1; off < 256; off <<= 1) {
        int x = sb[tid];
        if (tid >= off) x += sb[tid - off];
        __syncthreads();
        sb[tid] = x;
        __syncthreads();
    }
    if (tid < nb) part[tid] = sb[tid] - t;
}

__global__ void k_scan3(int* __restrict__ row_ptr, int* __restrict__ cursor,
                        const int* __restrict__ part, int n, int e) {
    int i = blockIdx.x * blockDim.x + threadIdx.x;
    if (i < n) {
        int v = row_ptr[i] + part[i >> 10];  // SCANB == 1024
        row_ptr[i] = v;
        cursor[i] = v;
    }
    if (i == 0) row_ptr[n] = e;
}

__global__ void k_scatter(const int* __restrict__ src, const int* __restrict__ dst,
                          int* __restrict__ cursor, int* __restrict__ col_idx, int e) {
    int i = blockIdx.x * blockDim.x + threadIdx.x;
    if (i < e) {
        int d = dst[i];
        int p = atomicAdd(&cursor[d], 1);
        col_idx[p] = src[i];
    }
}

// wx into X32[:,0:16]; ns = rsqrt(deg_out) (0 if isolated).
__global__ void k_init(const float* __restrict__ x, const float* __restrict__ cw,
                       const int* __restrict__ deg_out, float* __restrict__ X32,
                       float* __restrict__ ns, int n) {
    int t = blockIdx.x * blockDim.x + threadIdx.x;
    if (t >= n * 16) return;
    int node = t >> 4, f = t & 15;
    float xv = x[t];
    X32[node * 32 + f] = xv * cw[f];
    if (f == 0) {
        int dg = deg_out[node];
        ns[node] = dg > 0 ? rsqrtf((float)dg) : 0.f;
    }
}

// Fused 16-feature aggregation: m1 (SAGE mean of wx) and gcn1 agg, one x gather.
__global__ void k_agg16(const float* __restrict__ x, const float* __restrict__ cw,
                        const float* __restrict__ ns, const int* __restrict__ row_ptr,
                        const int* __restrict__ col_idx, float* __restrict__ X32,
                        float* __restrict__ g16, int n) {
    int t = blockIdx.x * blockDim.x + threadIdx.x;
    if (t >= n * 16) return;
    int node = t >> 4, f = t & 15;
    int r0 = row_ptr[node], r1 = row_ptr[node + 1];
    float am = 0.f, ah = 0.f;
    for (int j = r0; j < r1; ++j) {
        int s = col_idx[j];
        float xv = x[(s << 4) + f];
        am += xv;
        ah += xv * ns[s];
    }
    int dg = r1 - r0;
    X32[node * 32 + 16 + f] = cw[f] * am / (float)(dg > 0 ? dg : 1);
    float nd = dg > 0 ? rsqrtf((float)dg) : 0.f;
    g16[t] = ah * nd;
}

// a1n = relu(g16 @ Wg1 + bg1) * ns  (pre-scaled for the next aggregation).
__global__ void k_a1(const float* __restrict__ g16, const float* __restrict__ Wg1,
                     const float* __restrict__ bg1, const float* __restrict__ ns,
                     float* __restrict__ a1n, int n) {
    __shared__ float Wg1s[768];
    __shared__ float bg1s[48];
    for (int q = threadIdx.x; q < 768; q += 256) Wg1s[q] = Wg1[q];
    if (threadIdx.x < 48) bg1s[threadIdx.x] = bg1[threadIdx.x];
    __syncthreads();
    int gid = blockIdx.x * blockDim.x + threadIdx.x;
    if (gid >= n * 48) return;
    int node = gid / 48, c = gid - node * 48;
    float acc = bg1s[c];
    const float* g = &g16[node * 16];
#pragma unroll
    for (int k = 0; k < 16; ++k) acc += g[k] * Wg1s[k * 48 + c];
    a1n[gid] = fmaxf(acc, 0.f) * ns[node];
}

__global__ void k_agg48(const float* __restrict__ a1n, const int* __restrict__ row_ptr,
                        const int* __restrict__ col_idx, float* __restrict__ g48, int n) {
    int gid = blockIdx.x * blockDim.x + threadIdx.x;
    if (gid >= n * 48) return;
    int node = gid / 48, f = gid - node * 48;
    int r0 = row_ptr[node], r1 = row_ptr[node + 1];
    float acc = 0.f;
    for (int j = r0; j < r1; ++j) acc += a1n[col_idx[j] * 48 + f];
    int dg = r1 - r0;
    float nd = dg > 0 ? rsqrtf((float)dg) : 0.f;
    g48[gid] = acc * nd;
}

// Fused layer-1: out1 = relu([wx|m1]@[Ws1;Wn1] + b1) + wx@Wskip + bskip (bf16 out).
// Single K-tile (K=32 main, K=16 skip), all weights in LDS, 64x64 per block.
__launch_bounds__(256)
__global__ void k_l1(const float* __restrict__ X32, const float* __restrict__ Ws1,
                     const float* __restrict__ Wn1, const float* __restrict__ b1,
                     const float* __restrict__ Wskip, const float* __restrict__ bskip,
                     unsigned short* __restrict__ out1, int M) {
    __shared__ __align__(16) float As[32][64];
    __shared__ __align__(16) float Wm[32][64];
    __shared__ __align__(16) float Wk[16][64];
    const int tid = threadIdx.x;
    const int tx = tid & 15, ty = tid >> 4;
    const int row0 = blockIdx.x * 64, col0 = blockIdx.y * 64;
    const int ar = tid >> 2, ac8 = (tid & 3) << 3;
    const int arow = row0 + ar;
    float4 a0 = make_float4(0.f, 0.f, 0.f, 0.f), a1v = a0;
    if (arow < M) {
        a0  = *(const float4*)&X32[arow * 32 + ac8];
        a1v = *(const float4*)&X32[arow * 32 + ac8 + 4];
    }
    const int wkr = tid >> 4, wc4 = (tid & 15) << 2;
    const float4 wm0 = *(const float4*)&Ws1[wkr * 256 + col0 + wc4];
    const float4 wm1 = *(const float4*)&Wn1[wkr * 256 + col0 + wc4];
    const float4 wk0 = *(const float4*)&Wskip[wkr * 256 + col0 + wc4];
    As[ac8 + 0][ar] = a0.x;  As[ac8 + 1][ar] = a0.y;
    As[ac8 + 2][ar] = a0.z;  As[ac8 + 3][ar] = a0.w;
    As[ac8 + 4][ar] = a1v.x; As[ac8 + 5][ar] = a1v.y;
    As[ac8 + 6][ar] = a1v.z; As[ac8 + 7][ar] = a1v.w;
    *(float4*)&Wm[wkr][wc4]      = wm0;
    *(float4*)&Wm[16 + wkr][wc4] = wm1;
    *(float4*)&Wk[wkr][wc4]      = wk0;
    __syncthreads();

    float acc[4][4] = {{0.f}};
    float accs[4][4] = {{0.f}};
#pragma unroll
    for (int kk = 0; kk < 32; ++kk) {
        const float4 a = *(const float4*)&As[kk][tx << 2];
        const float4 w = *(const float4*)&Wm[kk][ty << 2];
        acc[0][0] += a.x * w.x; acc[0][1] += a.x * w.y; acc[0][2] += a.x * w.z; acc[0][3] += a.x * w.w;
        acc[1][0] += a.y * w.x; acc[1][1] += a.y * w.y; acc[1][2] += a.y * w.z; acc[1][3] += a.y * w.w;
        acc[2][0] += a.z * w.x; acc[2][1] += a.z * w.y; acc[2][2] += a.z * w.z; acc[2][3] += a.z * w.w;
        acc[3][0] += a.w * w.x; acc[3][1] += a.w * w.y; acc[3][2] += a.w * w.z; acc[3][3] += a.w * w.w;
    }
#pragma unroll
    for (int kk = 0; kk < 16; ++kk) {
        const float4 a = *(const float4*)&As[kk][tx << 2];
        const float4 w = *(const float4*)&Wk[kk][ty << 2];
        accs[0][0] += a.x * w.x; accs[0][1] += a.x * w.y; accs[0][2] += a.x * w.z; accs[0][3] += a.x * w.w;
        accs[1][0] += a.y * w.x; accs[1][1] += a.y * w.y; accs[1][2] += a.y * w.z; accs[1][3] += a.y * w.w;
        accs[2][0] += a.z * w.x; accs[2][1] += a.z * w.y; accs[2][2] += a.z * w.z; accs[2][3] += a.z * w.w;
        accs[3][0] += a.w * w.x; accs[3][1] += a.w * w.y; accs[3][2] += a.w * w.z; accs[3][3] += a.w * w.w;
    }
    const float4 bm = *(const float4*)&b1[col0 + (ty << 2)];
    const float4 bk = *(const float4*)&bskip[col0 + (ty << 2)];
#pragma unroll
    for (int i = 0; i < 4; ++i) {
        int row = row0 + (tx << 2) + i;
        if (row >= M) continue;
        float v0 = fmaxf(acc[i][0] + bm.x, 0.f) + accs[i][0] + bk.x;
        float v1 = fmaxf(acc[i][1] + bm.y, 0.f) + accs[i][1] + bk.y;
        float v2 = fmaxf(acc[i][2] + bm.z, 0.f) + accs[i][2] + bk.z;
        float v3 = fmaxf(acc[i][3] + bm.w, 0.f) + accs[i][3] + bk.w;
        ushort4 o;
        o.x = f2bf(v0); o.y = f2bf(v1); o.z = f2bf(v2); o.w = f2bf(v3);
        *(ushort4*)&out1[(size_t)row * 256 + col0 + (ty << 2)] = o;
    }
}

// m2 = mean of out1[src] per dst (bf16 in/out, fp32 accumulate).
__global__ void k_m2(const unsigned short* __restrict__ out1, const int* __restrict__ row_ptr,
                     const int* __restrict__ col_idx, unsigned short* __restrict__ m2, int n) {
    int node = blockIdx.x;
    int tid = threadIdx.x;
    int r0 = row_ptr[node], r1 = row_ptr[node + 1];
    float acc = 0.f;
    for (int j = r0; j < r1; ++j) {
        int s = col_idx[j];
        acc += bf2f(out1[(size_t)s * 256 + tid]);
    }
    int dg = r1 - r0;
    m2[(size_t)node * 256 + tid] = f2bf(acc / (float)(dg > 0 ? dg : 1));
}

// ---------------------------------------------------------------------------
// fp32 tiled GEMM (64x64 tile, BK=16, 4x4 micro-tile), split-K A/W pointers.
// ---------------------------------------------------------------------------
template <bool RELU>
__launch_bounds__(256)
__global__ void k_gemm(const float* __restrict__ A, const float* __restrict__ A2, int lda, int ksA,
                       const float* __restrict__ W, const float* __restrict__ W2, int ldw, int ksW,
                       const float* __restrict__ bias, float* __restrict__ out, int ldo,
                       int M, int K) {
    __shared__ __align__(16) float As[16][64];
    __shared__ __align__(16) float Ws[16][64];
    const int tid = threadIdx.x;
    const int tx = tid & 15, ty = tid >> 4;
    const int row0 = blockIdx.x * 64, col0 = blockIdx.y * 64;
    const int ar = tid >> 2, ac4 = (tid & 3) << 2;
    const int wk = tid >> 4, wc4 = (tid & 15) << 2;
    const int arow = row0 + ar;

    float acc[4][4] = {{0.f}};

    for (int k0 = 0; k0 < K; k0 += 16) {
        const float* Ap; int ka;
        if (k0 < ksA) { Ap = A; ka = k0; } else { Ap = A2; ka = k0 - ksA; }
        const float* Wp; int kw;
        if (k0 < ksW) { Wp = W; kw = k0; } else { Wp = W2; kw = k0 - ksW; }
        float4 av = make_float4(0.f, 0.f, 0.f, 0.f);
        if (arow < M) av = *(const float4*)&Ap[(size_t)arow * lda + ka + ac4];
        float4 wv = *(const float4*)&Wp[(size_t)(kw + wk) * ldw + col0 + wc4];
        __syncthreads();
        As[ac4 + 0][ar] = av.x; As[ac4 + 1][ar] = av.y;
        As[ac4 + 2][ar] = av.z; As[ac4 + 3][ar] = av.w;
        *(float4*)&Ws[wk][wc4] = wv;
        __syncthreads();
#pragma unroll
        for (int kk = 0; kk < 16; ++kk) {
            const float4 a = *(const float4*)&As[kk][tx << 2];
            const float4 w = *(const float4*)&Ws[kk][ty << 2];
            acc[0][0] += a.x * w.x; acc[0][1] += a.x * w.y; acc[0][2] += a.x * w.z; acc[0][3] += a.x * w.w;
            acc[1][0] += a.y * w.x; acc[1][1] += a.y * w.y; acc[1][2] += a.y * w.z; acc[1][3] += a.y * w.w;
            acc[2][0] += a.z * w.x; acc[2][1] += a.z * w.y; acc[2][2] += a.z * w.z; acc[2][3] += a.z * w.w;
            acc[3][0] += a.w * w.x; acc[3][1] += a.w * w.y; acc[3][2] += a.w * w.z; acc[3][3] += a.w * w.w;
        }
    }
    float4 bv = make_float4(0.f, 0.f, 0.f, 0.f);
    if (bias) bv = *(const float4*)&bias[col0 + (ty << 2)];
#pragma unroll
    for (int i = 0; i < 4; ++i) {
        int row = row0 + (tx << 2) + i;
        if (row >= M) continue;
        float4 v;
        v.x = acc[i][0] + bv.x; v.y = acc[i][1] + bv.y;
        v.z = acc[i][2] + bv.z; v.w = acc[i][3] + bv.w;
        if (RELU) {
            v.x = fmaxf(v.x, 0.f); v.y = fmaxf(v.y, 0.f);
            v.z = fmaxf(v.z, 0.f); v.w = fmaxf(v.w, 0.f);
        }
        *(float4*)&out[(size_t)row * ldo + col0 + (ty << 2)] = v;
    }
}

// Same GEMM but A/A2/resid are bf16 (fp32 LDS + compute). Used for emb (K=512).
__launch_bounds__(256)
__global__ void k_gemm_bfA(const unsigned short* __restrict__ A, const unsigned short* __restrict__ A2,
                           int lda, int ksA,
                           const float* __restrict__ W, const float* __restrict__ W2, int ldw, int ksW,
                           const float* __restrict__ bias,
                           const unsigned short* __restrict__ resid, int ldr,
                           float* __restrict__ out, int ldo, int M, int K) {
    __shared__ __align__(16) float As[16][64];
    __shared__ __align__(16) float Ws[16][64];
    const int tid = threadIdx.x;
    const int tx = tid & 15, ty = tid >> 4;
    const int row0 = blockIdx.x * 64, col0 = blockIdx.y * 64;
    const int ar = tid >> 2, ac4 = (tid & 3) << 2;
    const int wk = tid >> 4, wc4 = (tid & 15) << 2;
    const int arow = row0 + ar;

    float acc[4][4] = {{0.f}};

    for (int k0 = 0; k0 < K; k0 += 16) {
        const unsigned short* Ap; int ka;
        if (k0 < ksA) { Ap = A; ka = k0; } else { Ap = A2; ka = k0 - ksA; }
        const float* Wp; int kw;
        if (k0 < ksW) { Wp = W; kw = k0; } else { Wp = W2; kw = k0 - ksW; }
        ushort4 av = {0, 0, 0, 0};
        if (arow < M) av = *(const ushort4*)&Ap[(size_t)arow * lda + ka + ac4];
        float4 wv = *(const float4*)&Wp[(size_t)(kw + wk) * ldw + col0 + wc4];
        __syncthreads();
        As[ac4 + 0][ar] = bf2f(av.x); As[ac4 + 1][ar] = bf2f(av.y);
        As[ac4 + 2][ar] = bf2f(av.z); As[ac4 + 3][ar] = bf2f(av.w);
        *(float4*)&Ws[wk][wc4] = wv;
        __syncthreads();
#pragma unroll
        for (int kk = 0; kk < 16; ++kk) {
            const float4 a = *(const float4*)&As[kk][tx << 2];
            const float4 w = *(const float4*)&Ws[kk][ty << 2];
            acc[0][0] += a.x * w.x; acc[0][1] += a.x * w.y; acc[0][2] += a.x * w.z; acc[0][3] += a.x * w.w;
            acc[1][0] += a.y * w.x; acc[1][1] += a.y * w.y; acc[1][2] += a.y * w.z; acc[1][3] += a.y * w.w;
            acc[2][0] += a.z * w.x; acc[2][1] += a.z * w.y; acc[2][2] += a.z * w.z; acc[2][3] += a.z * w.w;
            acc[3][0] += a.w * w.x; acc[3][1] += a.w * w.y; acc[3][2] += a.w * w.z; acc[3][3] += a.w * w.w;
        }
    }
    const float4 bv = *(const float4*)&bias[col0 + (ty << 2)];
#pragma unroll
    for (int i = 0; i < 4; ++i) {
        int row = row0 + (tx << 2) + i;
        if (row >= M) continue;
        float4 v;
        v.x = fmaxf(acc[i][0] + bv.x, 0.f);
        v.y = fmaxf(acc[i][1] + bv.y, 0.f);
        v.z = fmaxf(acc[i][2] + bv.z, 0.f);
        v.w = fmaxf(acc[i][3] + bv.w, 0.f);
        const ushort4 r = *(const ushort4*)&resid[(size_t)row * ldr + col0 + (ty << 2)];
        v.x += bf2f(r.x); v.y += bf2f(r.y); v.z += bf2f(r.z); v.w += bf2f(r.w);
        *(float4*)&out[(size_t)row * ldo + col0 + (ty << 2)] = v;
    }
}

// scores[n] = emb[n,:] . Wfc + bfc  — one wave per node.
__global__ void k_scores(const float* __restrict__ emb, const float* __restrict__ Wfc,
                         const float* __restrict__ bfc, float* __restrict__ scores, int n) {
    int node = blockIdx.x * 4 + (threadIdx.x >> 6);
    int l = threadIdx.x & 63;
    if (node >= n) return;
    const float4 e = *(const float4*)&emb[(size_t)node * 256 + l * 4];
    const float4 w = *(const float4*)&Wfc[l * 4];
    float p = e.x * w.x + e.y * w.y + e.z * w.z + e.w * w.w;
    for (int off = 32; off > 0; off >>= 1) p += __shfl_down(p, off);
    if (l == 0) scores[node] = p + bfc[0];
}

__global__ void k_primary(const float* __restrict__ scores, const int* __restrict__ pairs,
                          float* __restrict__ out, int p) {
    int i = blockIdx.x * blockDim.x + threadIdx.x;
    if (i < p) {
        int a = pairs[2 * i], b = pairs[2 * i + 1];
        out[i] = sigmoidf_(scores[a] - scores[b]);
    }
}

// attn[n] = sigmoid(hid[n,:] . Wa2 + ba2) — one wave per node (128 feats).
__global__ void k_attn(const float* __restrict__ hid, const float* __restrict__ Wa2,
                       const float* __restrict__ ba2, float* __restrict__ out, int n) {
    int node = blockIdx.x * 4 + (threadIdx.x >> 6);
    int l = threadIdx.x & 63;
    if (node >= n) return;
    const float2 h = *(const float2*)&hid[(size_t)node * 128 + l * 2];
    const float2 w = *(const float2*)&Wa2[l * 2];
    float p = h.x * w.x + h.y * w.y;
    for (int off = 32; off > 0; off >>= 1) p += __shfl_down(p, off);
    if (l == 0) out[node] = sigmoidf_(p + ba2[0]);
}

extern "C" void kernel_launch(void* const* d_in, const int* in_sizes, int n_in,
                              void* d_out, int out_size, void* d_ws, size_t ws_size,
                              hipStream_t stream) {
    const float* x     = (const float*)d_in[0];
    const int*   src   = (const int*)d_in[1];
    const int*   dst   = (const int*)d_in[2];
    const int*   pairs = (const int*)d_in[3];
    const float* raw_w = (const float*)d_in[4];
    const float* Ws1   = (const float*)d_in[5];
    const float* Wn1   = (const float*)d_in[6];
    const float* b1    = (const float*)d_in[7];
    const float* Ws2   = (const float*)d_in[8];
    const float* Wn2   = (const float*)d_in[9];
    const float* b2    = (const float*)d_in[10];
    const float* Wskip = (const float*)d_in[11];
    const float* bskip = (const float*)d_in[12];
    const float* Wg1   = (const float*)d_in[13];
    const float* bg1   = (const float*)d_in[14];
    const float* Wg2   = (const float*)d_in[15];
    const float* bg2   = (const float*)d_in[16];
    const float* Wfc   = (const float*)d_in[17];
    const float* bfc   = (const float*)d_in[18];
    const float* Wa1   = (const float*)d_in[19];
    const float* ba1   = (const float*)d_in[20];
    const float* Wa2   = (const float*)d_in[21];
    const float* ba2   = (const float*)d_in[22];

    const int N = in_sizes[0] / 16;
    const int E = in_sizes[1];
    const int P = in_sizes[3] / 2;

    // ---- workspace layout (~130 MB total) ----
    char* base = (char*)d_ws;
    size_t off = 0;
    auto alloc = [&](size_t bytes) -> char* {
        char* p = base + off;
        off = (off + bytes + 255) & ~(size_t)255;
        return p;
    };
    float* cw      = (float*)alloc(16 * 4);
    float* ns      = (float*)alloc((size_t)N * 4);
    float* scores  = (float*)alloc((size_t)N * 4);
    int*   deg     = (int*)alloc((size_t)2 * N * 4);
    int*   deg_in  = deg;
    int*   deg_out = deg + N;
    int*   row_ptr = (int*)alloc((size_t)(N + 1) * 4);
    int*   part    = (int*)alloc(256 * 4);
    int*   col_idx = (int*)alloc((size_t)E * 4);
    float* X32     = (float*)alloc((size_t)N * 32 * 4);
    float* g16     = (float*)alloc((size_t)N * 16 * 4);
    char*  bigA    = alloc((size_t)N * 256 * 2);   // out1(bf16) -> hid(f32 N*128)
    char*  bigB    = alloc((size_t)N * 256 * 2);   // m2(bf16)  -> a1n+g48 (f32)
    if (off > ws_size) return;  // ws too small: output stays zero (visible failure)

    int* cursor = deg_in;  // deg_in dead after scan1; reuse as scatter cursor

    unsigned short* out1 = (unsigned short*)bigA;
    float*          hid  = (float*)bigA;
    unsigned short* m2   = (unsigned short*)bigB;
    float*          a1n  = (float*)bigB;
    float*          g48  = (float*)(bigB + (size_t)N * 48 * 4);

    float* out         = (float*)d_out;
    float* out_primary = out;
    float* out_aux     = out + P;            // also doubles as emb scratch
    float* out_attn    = out + P + (size_t)N * 256;
    float* emb         = out_aux;

    const int gE   = (E + 255) / 256;
    const int NB   = (N + SCANB - 1) / SCANB;
    const int g16t = (N * 16 + 255) / 256;
    const int g48t = (N * 48 + 255) / 256;
    const int MB   = (N + 63) / 64;
    dim3 blk(256);

    // ---- CSR build ----
    hipMemsetAsync(deg, 0, (size_t)2 * N * 4, stream);
    k_cw<<<1, 64, 0, stream>>>(raw_w, cw, 16);
    k_hist<<<gE, blk, 0, stream>>>(src, dst, deg_in, deg_out, E);
    k_scan1<<<NB, blk, 0, stream>>>(deg_in, row_ptr, part, N);
    k_scan2<<<1, blk, 0, stream>>>(part, NB);
    k_scan3<<<(N + 255) / 256, blk, 0, stream>>>(row_ptr, cursor, part, N, E);
    k_scatter<<<gE, blk, 0, stream>>>(src, dst, cursor, col_idx, E);

    // ---- node features / layer-1 ----
    k_init<<<g16t, blk, 0, stream>>>(x, cw, deg_out, X32, ns, N);
    k_agg16<<<g16t, blk, 0, stream>>>(x, cw, ns, row_ptr, col_idx, X32, g16, N);
    k_l1<<<dim3(MB, 4), blk, 0, stream>>>(X32, Ws1, Wn1, b1, Wskip, bskip, out1, N);

    // ---- layer 2 (emb lives in out_aux region until aux branch runs) ----
    k_m2<<<N, blk, 0, stream>>>(out1, row_ptr, col_idx, m2, N);
    k_gemm_bfA<<<dim3(MB, 4), blk, 0, stream>>>(out1, m2, 256, 256,
                                                Ws2, Wn2, 256, 256,
                                                b2, out1, 256, emb, 256, N, 512);

    // ---- heads (consume emb before aux overwrites it) ----
    k_scores<<<(N + 3) / 4, blk, 0, stream>>>(emb, Wfc, bfc, scores, N);
    k_primary<<<(P + 255) / 256, blk, 0, stream>>>(scores, pairs, out_primary, P);
    k_gemm<true><<<dim3(MB, 2), blk, 0, stream>>>(emb, nullptr, 256, 256,
                                                  Wa1, nullptr, 128, 256,
                                                  ba1, hid, 128, N, 256);
    k_attn<<<(N + 3) / 4, blk, 0, stream>>>(hid, Wa2, ba2, out_attn, N);

    // ---- auxiliary criteria-relation branch (writes real aux output last) ----
    k_a1<<<g48t, blk, 0, stream>>>(g16, Wg1, bg1, ns, a1n, N);
    k_agg48<<<g48t, blk, 0, stream>>>(a1n, row_ptr, col_idx, g48, N);
    k_gemm<false><<<dim3(MB, 4), blk, 0, stream>>>(g48, nullptr, 48, 48,
                                                   Wg2, nullptr, 256, 48,
                                                   bg2, out_aux, 256, N, 48);
}

// Round 4
// 1221.789 us; speedup vs baseline: 1.3209x; 1.3209x over previous
//
#include <hip/hip_runtime.h>
#include <hip/hip_bf16.h>
#include <math.h>

// ---------------------------------------------------------------------------
// GNN model on MI355X. N=100000, E=1600000, IN_F=16, H_F=256, C=16.
//   CSR build -> k_init/k_agg16 -> k_l1 (fused skip+layer1, bf16 out1)
//   -> k_m2 (bf16 mean) -> emb GEMM (bf16 MFMA, K=512, emb in d_out aux
//   region) -> scores/primary + attn GEMM (bf16 MFMA) -> aux branch last.
// R3: emb GEMM was VALU-bound fp32 (457us, MfmaUtil=0, VALUBusy=73%).
// R4: both big GEMMs -> mfma_f32_16x16x32_bf16 (weights bf16-transposed
//     per launch). Predicted emb ~70-110us, attn ~30us.
// ---------------------------------------------------------------------------

#define SCANB 1024

typedef __attribute__((ext_vector_type(8))) short bf16x8;
typedef __attribute__((ext_vector_type(4))) float f32x4;

__device__ __forceinline__ float sigmoidf_(float x) { return 1.0f / (1.0f + expf(-x)); }

__device__ __forceinline__ float bf2f(unsigned short u) {
    union { unsigned int i; float f; } c;
    c.i = ((unsigned int)u) << 16;
    return c.f;
}
__device__ __forceinline__ unsigned short f2bf(float f) {
    union { float f; unsigned int i; } c;
    c.f = f;
    unsigned int x = c.i;
    x += 0x7fffu + ((x >> 16) & 1u);  // round-to-nearest-even
    return (unsigned short)(x >> 16);
}

// softmax over the 16-element criteria weight vector.
__global__ void k_cw(const float* __restrict__ rw, float* __restrict__ cw, int c) {
    if (threadIdx.x == 0 && blockIdx.x == 0) {
        float mx = -1e30f;
        for (int i = 0; i < c; ++i) mx = fmaxf(mx, rw[i]);
        float s = 0.f;
        for (int i = 0; i < c; ++i) s += expf(rw[i] - mx);
        for (int i = 0; i < c; ++i) cw[i] = expf(rw[i] - mx) / s;
    }
}

__global__ void k_hist(const int* __restrict__ src, const int* __restrict__ dst,
                       int* __restrict__ deg_in, int* __restrict__ deg_out, int e) {
    int i = blockIdx.x * blockDim.x + threadIdx.x;
    if (i < e) {
        atomicAdd(&deg_in[dst[i]], 1);
        atomicAdd(&deg_out[src[i]], 1);
    }
}

// Block-local exclusive scan of deg (SCANB elems / 256-thread block).
__global__ void k_scan1(const int* __restrict__ deg, int* __restrict__ local,
                        int* __restrict__ part, int n) {
    __shared__ int sb[256];
    const int tid = threadIdx.x;
    const int i0 = blockIdx.x * SCANB + tid * 4;
    int v[4];
#pragma unroll
    for (int j = 0; j < 4; ++j) v[j] = (i0 + j < n) ? deg[i0 + j] : 0;
    int t = v[0] + v[1] + v[2] + v[3];
    sb[tid] = t;
    __syncthreads();
    for (int off = 1; off < 256; off <<= 1) {
        int x = sb[tid];
        if (tid >= off) x += sb[tid - off];
        __syncthreads();
        sb[tid] = x;
        __syncthreads();
    }
    int incl = sb[tid];
    int ex = incl - t;
    if (tid == 255) part[blockIdx.x] = incl;
    int p = ex;
#pragma unroll
    for (int j = 0; j < 4; ++j) {
        if (i0 + j < n) local[i0 + j] = p;
        p += v[j];
    }
}

__global__ void k_scan2(int* __restrict__ part, int nb) {
    __shared__ int sb[256];
    const int tid = threadIdx.x;
    int t = (tid < nb) ? part[tid] : 0;
    sb[tid] = t;
    __syncthreads();
    for (int off = 1; off < 256; off <<= 1) {
        int x = sb[tid];
        if (tid >= off) x += sb[tid - off];
        __syncthreads();
        sb[tid] = x;
        __syncthreads();
    }
    if (tid < nb) part[tid] = sb[tid] - t;
}

__global__ void k_scan3(int* __restrict__ row_ptr, int* __restrict__ cursor,
                        const int* __restrict__ part, int n, int e) {
    int i = blockIdx.x * blockDim.x + threadIdx.x;
    if (i < n) {
        int v = row_ptr[i] + part[i >> 10];  // SCANB == 1024
        row_ptr[i] = v;
        cursor[i] = v;
    }
    if (i == 0) row_ptr[n] = e;
}

__global__ void k_scatter(const int* __restrict__ src, const int* __restrict__ dst,
                          int* __restrict__ cursor, int* __restrict__ col_idx, int e) {
    int i = blockIdx.x * blockDim.x + threadIdx.x;
    if (i < e) {
        int d = dst[i];
        int p = atomicAdd(&cursor[d], 1);
        col_idx[p] = src[i];
    }
}

// wx into X32[:,0:16]; ns = rsqrt(deg_out) (0 if isolated).
__global__ void k_init(const float* __restrict__ x, const float* __restrict__ cw,
                       const int* __restrict__ deg_out, float* __restrict__ X32,
                       float* __restrict__ ns, int n) {
    int t = blockIdx.x * blockDim.x + threadIdx.x;
    if (t >= n * 16) return;
    int node = t >> 4, f = t & 15;
    float xv = x[t];
    X32[node * 32 + f] = xv * cw[f];
    if (f == 0) {
        int dg = deg_out[node];
        ns[node] = dg > 0 ? rsqrtf((float)dg) : 0.f;
    }
}

// Fused 16-feature aggregation: m1 (SAGE mean of wx) and gcn1 agg, one x gather.
__global__ void k_agg16(const float* __restrict__ x, const float* __restrict__ cw,
                        const float* __restrict__ ns, const int* __restrict__ row_ptr,
                        const int* __restrict__ col_idx, float* __restrict__ X32,
                        float* __restrict__ g16, int n) {
    int t = blockIdx.x * blockDim.x + threadIdx.x;
    if (t >= n * 16) return;
    int node = t >> 4, f = t & 15;
    int r0 = row_ptr[node], r1 = row_ptr[node + 1];
    float am = 0.f, ah = 0.f;
    for (int j = r0; j < r1; ++j) {
        int s = col_idx[j];
        float xv = x[(s << 4) + f];
        am += xv;
        ah += xv * ns[s];
    }
    int dg = r1 - r0;
    X32[node * 32 + 16 + f] = cw[f] * am / (float)(dg > 0 ? dg : 1);
    float nd = dg > 0 ? rsqrtf((float)dg) : 0.f;
    g16[t] = ah * nd;
}

// a1n = relu(g16 @ Wg1 + bg1) * ns  (pre-scaled for the next aggregation).
__global__ void k_a1(const float* __restrict__ g16, const float* __restrict__ Wg1,
                     const float* __restrict__ bg1, const float* __restrict__ ns,
                     float* __restrict__ a1n, int n) {
    __shared__ float Wg1s[768];
    __shared__ float bg1s[48];
    for (int q = threadIdx.x; q < 768; q += 256) Wg1s[q] = Wg1[q];
    if (threadIdx.x < 48) bg1s[threadIdx.x] = bg1[threadIdx.x];
    __syncthreads();
    int gid = blockIdx.x * blockDim.x + threadIdx.x;
    if (gid >= n * 48) return;
    int node = gid / 48, c = gid - node * 48;
    float acc = bg1s[c];
    const float* g = &g16[node * 16];
#pragma unroll
    for (int k = 0; k < 16; ++k) acc += g[k] * Wg1s[k * 48 + c];
    a1n[gid] = fmaxf(acc, 0.f) * ns[node];
}

__global__ void k_agg48(const float* __restrict__ a1n, const int* __restrict__ row_ptr,
                        const int* __restrict__ col_idx, float* __restrict__ g48, int n) {
    int gid = blockIdx.x * blockDim.x + threadIdx.x;
    if (gid >= n * 48) return;
    int node = gid / 48, f = gid - node * 48;
    int r0 = row_ptr[node], r1 = row_ptr[node + 1];
    float acc = 0.f;
    for (int j = r0; j < r1; ++j) acc += a1n[col_idx[j] * 48 + f];
    int dg = r1 - r0;
    float nd = dg > 0 ? rsqrtf((float)dg) : 0.f;
    g48[gid] = acc * nd;
}

// Fused layer-1: out1 = relu([wx|m1]@[Ws1;Wn1] + b1) + wx@Wskip + bskip (bf16 out).
__launch_bounds__(256)
__global__ void k_l1(const float* __restrict__ X32, const float* __restrict__ Ws1,
                     const float* __restrict__ Wn1, const float* __restrict__ b1,
                     const float* __restrict__ Wskip, const float* __restrict__ bskip,
                     unsigned short* __restrict__ out1, int M) {
    __shared__ __align__(16) float As[32][64];
    __shared__ __align__(16) float Wm[32][64];
    __shared__ __align__(16) float Wk[16][64];
    const int tid = threadIdx.x;
    const int tx = tid & 15, ty = tid >> 4;
    const int row0 = blockIdx.x * 64, col0 = blockIdx.y * 64;
    const int ar = tid >> 2, ac8 = (tid & 3) << 3;
    const int arow = row0 + ar;
    float4 a0 = make_float4(0.f, 0.f, 0.f, 0.f), a1v = a0;
    if (arow < M) {
        a0  = *(const float4*)&X32[arow * 32 + ac8];
        a1v = *(const float4*)&X32[arow * 32 + ac8 + 4];
    }
    const int wkr = tid >> 4, wc4 = (tid & 15) << 2;
    const float4 wm0 = *(const float4*)&Ws1[wkr * 256 + col0 + wc4];
    const float4 wm1 = *(const float4*)&Wn1[wkr * 256 + col0 + wc4];
    const float4 wk0 = *(const float4*)&Wskip[wkr * 256 + col0 + wc4];
    As[ac8 + 0][ar] = a0.x;  As[ac8 + 1][ar] = a0.y;
    As[ac8 + 2][ar] = a0.z;  As[ac8 + 3][ar] = a0.w;
    As[ac8 + 4][ar] = a1v.x; As[ac8 + 5][ar] = a1v.y;
    As[ac8 + 6][ar] = a1v.z; As[ac8 + 7][ar] = a1v.w;
    *(float4*)&Wm[wkr][wc4]      = wm0;
    *(float4*)&Wm[16 + wkr][wc4] = wm1;
    *(float4*)&Wk[wkr][wc4]      = wk0;
    __syncthreads();

    float acc[4][4] = {{0.f}};
    float accs[4][4] = {{0.f}};
#pragma unroll
    for (int kk = 0; kk < 32; ++kk) {
        const float4 a = *(const float4*)&As[kk][tx << 2];
        const float4 w = *(const float4*)&Wm[kk][ty << 2];
        acc[0][0] += a.x * w.x; acc[0][1] += a.x * w.y; acc[0][2] += a.x * w.z; acc[0][3] += a.x * w.w;
        acc[1][0] += a.y * w.x; acc[1][1] += a.y * w.y; acc[1][2] += a.y * w.z; acc[1][3] += a.y * w.w;
        acc[2][0] += a.z * w.x; acc[2][1] += a.z * w.y; acc[2][2] += a.z * w.z; acc[2][3] += a.z * w.w;
        acc[3][0] += a.w * w.x; acc[3][1] += a.w * w.y; acc[3][2] += a.w * w.z; acc[3][3] += a.w * w.w;
    }
#pragma unroll
    for (int kk = 0; kk < 16; ++kk) {
        const float4 a = *(const float4*)&As[kk][tx << 2];
        const float4 w = *(const float4*)&Wk[kk][ty << 2];
        accs[0][0] += a.x * w.x; accs[0][1] += a.x * w.y; accs[0][2] += a.x * w.z; accs[0][3] += a.x * w.w;
        accs[1][0] += a.y * w.x; accs[1][1] += a.y * w.y; accs[1][2] += a.y * w.z; accs[1][3] += a.y * w.w;
        accs[2][0] += a.z * w.x; accs[2][1] += a.z * w.y; accs[2][2] += a.z * w.z; accs[2][3] += a.z * w.w;
        accs[3][0] += a.w * w.x; accs[3][1] += a.w * w.y; accs[3][2] += a.w * w.z; accs[3][3] += a.w * w.w;
    }
    const float4 bm = *(const float4*)&b1[col0 + (ty << 2)];
    const float4 bk = *(const float4*)&bskip[col0 + (ty << 2)];
#pragma unroll
    for (int i = 0; i < 4; ++i) {
        int row = row0 + (tx << 2) + i;
        if (row >= M) continue;
        float v0 = fmaxf(acc[i][0] + bm.x, 0.f) + accs[i][0] + bk.x;
        float v1 = fmaxf(acc[i][1] + bm.y, 0.f) + accs[i][1] + bk.y;
        float v2 = fmaxf(acc[i][2] + bm.z, 0.f) + accs[i][2] + bk.z;
        float v3 = fmaxf(acc[i][3] + bm.w, 0.f) + accs[i][3] + bk.w;
        ushort4 o;
        o.x = f2bf(v0); o.y = f2bf(v1); o.z = f2bf(v2); o.w = f2bf(v3);
        *(ushort4*)&out1[(size_t)row * 256 + col0 + (ty << 2)] = o;
    }
}

// m2 = mean of out1[src] per dst (bf16 in/out, fp32 accumulate).
__global__ void k_m2(const unsigned short* __restrict__ out1, const int* __restrict__ row_ptr,
                     const int* __restrict__ col_idx, unsigned short* __restrict__ m2, int n) {
    int node = blockIdx.x;
    int tid = threadIdx.x;
    int r0 = row_ptr[node], r1 = row_ptr[node + 1];
    float acc = 0.f;
    for (int j = r0; j < r1; ++j) {
        int s = col_idx[j];
        acc += bf2f(out1[(size_t)s * 256 + tid]);
    }
    int dg = r1 - r0;
    m2[(size_t)node * 256 + tid] = f2bf(acc / (float)(dg > 0 ? dg : 1));
}

// Transpose-convert fp32 weight [K,Ncol] -> bf16 K-major [Ncol][ldK] at koff.
__global__ void k_w2bf(const float* __restrict__ W, unsigned short* __restrict__ o,
                       int K, int Ncol, int ldK, int koff) {
    int i = blockIdx.x * blockDim.x + threadIdx.x;
    if (i >= K * Ncol) return;
    int c = i / K, k = i - c * K;
    o[(size_t)c * ldK + koff + k] = f2bf(W[(size_t)k * Ncol + c]);
}

// ---------------------------------------------------------------------------
// bf16 MFMA GEMM: out[M,Nc] = relu(A[M,Ktot] @ B + bias) (+ resid).
// A row-major (split at K=256 into A1/A2 when !AF32; fp32 single buf when
// AF32). Bt = B transposed, bf16 [Nc][Ktot]. 128x128 block tile, BK=32,
// 4 waves 2x2, each 64x64 via 4x4 16x16x32 frags. LDS rows padded to 40
// ushorts (20-dword stride -> <=2-way bank alias, free).
// Frag layout (m89-verified): A/B lane l holds 8 contig k at idx l&15,
// k=(l>>4)*8+j ; C/D col=lane&15, row=(lane>>4)*4+reg.
// ---------------------------------------------------------------------------
template <bool AF32, bool RESID>
__launch_bounds__(256)
__global__ void k_gemm_mf(const void* __restrict__ A1, const void* __restrict__ A2,
                          const unsigned short* __restrict__ Bt,
                          const float* __restrict__ bias,
                          const unsigned short* __restrict__ resid,
                          float* __restrict__ out, int ldo, int M, int Ktot) {
    __shared__ __align__(16) unsigned short As[128][40];
    __shared__ __align__(16) unsigned short Bs[128][40];
    const int tid = threadIdx.x;
    const int lane = tid & 63, wave = tid >> 6;
    const int wr = wave >> 1, wc = wave & 1;
    const int fi = lane & 15, koct = lane >> 4;
    const int srow = tid >> 1, shalf = tid & 1;
    const int row0 = blockIdx.x * 128, col0 = blockIdx.y * 128;
    const int arow = row0 + srow;

    f32x4 acc[4][4];
#pragma unroll
    for (int r = 0; r < 4; ++r)
#pragma unroll
        for (int c = 0; c < 4; ++c) acc[r][c] = (f32x4){0.f, 0.f, 0.f, 0.f};

    for (int k0 = 0; k0 < Ktot; k0 += 32) {
        uint4 a0 = {0, 0, 0, 0}, a1 = {0, 0, 0, 0};
        if (AF32) {
            if (arow < M) {
                const float* Af = (const float*)A1;
                const size_t p = (size_t)arow * Ktot + k0 + shalf * 16;
                const float4 f0 = *(const float4*)&Af[p + 0];
                const float4 f1 = *(const float4*)&Af[p + 4];
                const float4 f2 = *(const float4*)&Af[p + 8];
                const float4 f3 = *(const float4*)&Af[p + 12];
                union { uint4 v[2]; unsigned short s[16]; } pk;
                pk.s[0] = f2bf(f0.x);  pk.s[1] = f2bf(f0.y);
                pk.s[2] = f2bf(f0.z);  pk.s[3] = f2bf(f0.w);
                pk.s[4] = f2bf(f1.x);  pk.s[5] = f2bf(f1.y);
                pk.s[6] = f2bf(f1.z);  pk.s[7] = f2bf(f1.w);
                pk.s[8] = f2bf(f2.x);  pk.s[9] = f2bf(f2.y);
                pk.s[10] = f2bf(f2.z); pk.s[11] = f2bf(f2.w);
                pk.s[12] = f2bf(f3.x); pk.s[13] = f2bf(f3.y);
                pk.s[14] = f2bf(f3.z); pk.s[15] = f2bf(f3.w);
                a0 = pk.v[0]; a1 = pk.v[1];
            }
        } else {
            const unsigned short* Ap = (const unsigned short*)((k0 < 256) ? A1 : A2);
            const int ka = k0 & 255;
            if (arow < M) {
                const size_t p = (size_t)arow * 256 + ka + shalf * 16;
                a0 = *(const uint4*)&Ap[p];
                a1 = *(const uint4*)&Ap[p + 8];
            }
        }
        const size_t pb = (size_t)(col0 + srow) * Ktot + k0 + shalf * 16;
        const uint4 b0 = *(const uint4*)&Bt[pb];
        const uint4 b1 = *(const uint4*)&Bt[pb + 8];
        __syncthreads();
        *(uint4*)&As[srow][shalf * 16 + 0] = a0;
        *(uint4*)&As[srow][shalf * 16 + 8] = a1;
        *(uint4*)&Bs[srow][shalf * 16 + 0] = b0;
        *(uint4*)&Bs[srow][shalf * 16 + 8] = b1;
        __syncthreads();
        bf16x8 af[4], bf[4];
#pragma unroll
        for (int r = 0; r < 4; ++r)
            af[r] = *(const bf16x8*)&As[wr * 64 + r * 16 + fi][koct * 8];
#pragma unroll
        for (int c = 0; c < 4; ++c)
            bf[c] = *(const bf16x8*)&Bs[wc * 64 + c * 16 + fi][koct * 8];
#pragma unroll
        for (int r = 0; r < 4; ++r)
#pragma unroll
            for (int c = 0; c < 4; ++c)
                acc[r][c] = __builtin_amdgcn_mfma_f32_16x16x32_bf16(af[r], bf[c], acc[r][c], 0, 0, 0);
    }

#pragma unroll
    for (int r = 0; r < 4; ++r) {
        const int rowb = row0 + wr * 64 + r * 16 + koct * 4;
#pragma unroll
        for (int c = 0; c < 4; ++c) {
            const int col = col0 + wc * 64 + c * 16 + fi;
            const float bv = bias[col];
#pragma unroll
            for (int q = 0; q < 4; ++q) {
                const int rr = rowb + q;
                if (rr >= M) continue;
                float v = fmaxf(acc[r][c][q] + bv, 0.f);
                if (RESID) v += bf2f(resid[(size_t)rr * 256 + col]);
                out[(size_t)rr * ldo + col] = v;
            }
        }
    }
}

// ---------------------------------------------------------------------------
// fp32 tiled GEMM (64x64 tile, BK=16, 4x4 micro-tile) — used for aux (K=48).
// ---------------------------------------------------------------------------
template <bool RELU>
__launch_bounds__(256)
__global__ void k_gemm(const float* __restrict__ A, const float* __restrict__ A2, int lda, int ksA,
                       const float* __restrict__ W, const float* __restrict__ W2, int ldw, int ksW,
                       const float* __restrict__ bias, float* __restrict__ out, int ldo,
                       int M, int K) {
    __shared__ __align__(16) float As[16][64];
    __shared__ __align__(16) float Ws[16][64];
    const int tid = threadIdx.x;
    const int tx = tid & 15, ty = tid >> 4;
    const int row0 = blockIdx.x * 64, col0 = blockIdx.y * 64;
    const int ar = tid >> 2, ac4 = (tid & 3) << 2;
    const int wk = tid >> 4, wc4 = (tid & 15) << 2;
    const int arow = row0 + ar;

    float acc[4][4] = {{0.f}};

    for (int k0 = 0; k0 < K; k0 += 16) {
        const float* Ap; int ka;
        if (k0 < ksA) { Ap = A; ka = k0; } else { Ap = A2; ka = k0 - ksA; }
        const float* Wp; int kw;
        if (k0 < ksW) { Wp = W; kw = k0; } else { Wp = W2; kw = k0 - ksW; }
        float4 av = make_float4(0.f, 0.f, 0.f, 0.f);
        if (arow < M) av = *(const float4*)&Ap[(size_t)arow * lda + ka + ac4];
        float4 wv = *(const float4*)&Wp[(size_t)(kw + wk) * ldw + col0 + wc4];
        __syncthreads();
        As[ac4 + 0][ar] = av.x; As[ac4 + 1][ar] = av.y;
        As[ac4 + 2][ar] = av.z; As[ac4 + 3][ar] = av.w;
        *(float4*)&Ws[wk][wc4] = wv;
        __syncthreads();
#pragma unroll
        for (int kk = 0; kk < 16; ++kk) {
            const float4 a = *(const float4*)&As[kk][tx << 2];
            const float4 w = *(const float4*)&Ws[kk][ty << 2];
            acc[0][0] += a.x * w.x; acc[0][1] += a.x * w.y; acc[0][2] += a.x * w.z; acc[0][3] += a.x * w.w;
            acc[1][0] += a.y * w.x; acc[1][1] += a.y * w.y; acc[1][2] += a.y * w.z; acc[1][3] += a.y * w.w;
            acc[2][0] += a.z * w.x; acc[2][1] += a.z * w.y; acc[2][2] += a.z * w.z; acc[2][3] += a.z * w.w;
            acc[3][0] += a.w * w.x; acc[3][1] += a.w * w.y; acc[3][2] += a.w * w.z; acc[3][3] += a.w * w.w;
        }
    }
    float4 bv = make_float4(0.f, 0.f, 0.f, 0.f);
    if (bias) bv = *(const float4*)&bias[col0 + (ty << 2)];
#pragma unroll
    for (int i = 0; i < 4; ++i) {
        int row = row0 + (tx << 2) + i;
        if (row >= M) continue;
        float4 v;
        v.x = acc[i][0] + bv.x; v.y = acc[i][1] + bv.y;
        v.z = acc[i][2] + bv.z; v.w = acc[i][3] + bv.w;
        if (RELU) {
            v.x = fmaxf(v.x, 0.f); v.y = fmaxf(v.y, 0.f);
            v.z = fmaxf(v.z, 0.f); v.w = fmaxf(v.w, 0.f);
        }
        *(float4*)&out[(size_t)row * ldo + col0 + (ty << 2)] = v;
    }
}

// scores[n] = emb[n,:] . Wfc + bfc  — one wave per node.
__global__ void k_scores(const float* __restrict__ emb, const float* __restrict__ Wfc,
                         const float* __restrict__ bfc, float* __restrict__ scores, int n) {
    int node = blockIdx.x * 4 + (threadIdx.x >> 6);
    int l = threadIdx.x & 63;
    if (node >= n) return;
    const float4 e = *(const float4*)&emb[(size_t)node * 256 + l * 4];
    const float4 w = *(const float4*)&Wfc[l * 4];
    float p = e.x * w.x + e.y * w.y + e.z * w.z + e.w * w.w;
    for (int off = 32; off > 0; off >>= 1) p += __shfl_down(p, off);
    if (l == 0) scores[node] = p + bfc[0];
}

__global__ void k_primary(const float* __restrict__ scores, const int* __restrict__ pairs,
                          float* __restrict__ out, int p) {
    int i = blockIdx.x * blockDim.x + threadIdx.x;
    if (i < p) {
        int a = pairs[2 * i], b = pairs[2 * i + 1];
        out[i] = sigmoidf_(scores[a] - scores[b]);
    }
}

// attn[n] = sigmoid(hid[n,:] . Wa2 + ba2) — one wave per node (128 feats).
__global__ void k_attn(const float* __restrict__ hid, const float* __restrict__ Wa2,
                       const float* __restrict__ ba2, float* __restrict__ out, int n) {
    int node = blockIdx.x * 4 + (threadIdx.x >> 6);
    int l = threadIdx.x & 63;
    if (node >= n) return;
    const float2 h = *(const float2*)&hid[(size_t)node * 128 + l * 2];
    const float2 w = *(const float2*)&Wa2[l * 2];
    float p = h.x * w.x + h.y * w.y;
    for (int off = 32; off > 0; off >>= 1) p += __shfl_down(p, off);
    if (l == 0) out[node] = sigmoidf_(p + ba2[0]);
}

extern "C" void kernel_launch(void* const* d_in, const int* in_sizes, int n_in,
                              void* d_out, int out_size, void* d_ws, size_t ws_size,
                              hipStream_t stream) {
    const float* x     = (const float*)d_in[0];
    const int*   src   = (const int*)d_in[1];
    const int*   dst   = (const int*)d_in[2];
    const int*   pairs = (const int*)d_in[3];
    const float* raw_w = (const float*)d_in[4];
    const float* Ws1   = (const float*)d_in[5];
    const float* Wn1   = (const float*)d_in[6];
    const float* b1    = (const float*)d_in[7];
    const float* Ws2   = (const float*)d_in[8];
    const float* Wn2   = (const float*)d_in[9];
    const float* b2    = (const float*)d_in[10];
    const float* Wskip = (const float*)d_in[11];
    const float* bskip = (const float*)d_in[12];
    const float* Wg1   = (const float*)d_in[13];
    const float* bg1   = (const float*)d_in[14];
    const float* Wg2   = (const float*)d_in[15];
    const float* bg2   = (const float*)d_in[16];
    const float* Wfc   = (const float*)d_in[17];
    const float* bfc   = (const float*)d_in[18];
    const float* Wa1   = (const float*)d_in[19];
    const float* ba1   = (const float*)d_in[20];
    const float* Wa2   = (const float*)d_in[21];
    const float* ba2   = (const float*)d_in[22];

    const int N = in_sizes[0] / 16;
    const int E = in_sizes[1];
    const int P = in_sizes[3] / 2;

    // ---- workspace layout (~130 MB total) ----
    char* base = (char*)d_ws;
    size_t off = 0;
    auto alloc = [&](size_t bytes) -> char* {
        char* p = base + off;
        off = (off + bytes + 255) & ~(size_t)255;
        return p;
    };
    float* cw      = (float*)alloc(16 * 4);
    float* ns      = (float*)alloc((size_t)N * 4);
    float* scores  = (float*)alloc((size_t)N * 4);
    int*   deg     = (int*)alloc((size_t)2 * N * 4);
    int*   deg_in  = deg;
    int*   deg_out = deg + N;
    int*   row_ptr = (int*)alloc((size_t)(N + 1) * 4);
    int*   part    = (int*)alloc(256 * 4);
    int*   col_idx = (int*)alloc((size_t)E * 4);
    float* X32     = (float*)alloc((size_t)N * 32 * 4);
    float* g16     = (float*)alloc((size_t)N * 16 * 4);
    unsigned short* Wt_emb = (unsigned short*)alloc(256 * 512 * 2);  // [256 cols][512 k]
    unsigned short* Wt_a1  = (unsigned short*)alloc(128 * 256 * 2);  // [128 cols][256 k]
    char*  bigA    = alloc((size_t)N * 256 * 2);   // out1(bf16) -> hid(f32 N*128)
    char*  bigB    = alloc((size_t)N * 256 * 2);   // m2(bf16)  -> a1n+g48 (f32)
    if (off > ws_size) return;  // ws too small: output stays zero (visible failure)

    int* cursor = deg_in;  // deg_in dead after scan1; reuse as scatter cursor

    unsigned short* out1 = (unsigned short*)bigA;
    float*          hid  = (float*)bigA;
    unsigned short* m2   = (unsigned short*)bigB;
    float*          a1n  = (float*)bigB;
    float*          g48  = (float*)(bigB + (size_t)N * 48 * 4);

    float* out         = (float*)d_out;
    float* out_primary = out;
    float* out_aux     = out + P;            // also doubles as emb scratch
    float* out_attn    = out + P + (size_t)N * 256;
    float* emb         = out_aux;

    const int gE   = (E + 255) / 256;
    const int NB   = (N + SCANB - 1) / SCANB;
    const int g16t = (N * 16 + 255) / 256;
    const int g48t = (N * 48 + 255) / 256;
    const int MB   = (N + 63) / 64;
    const int MBT  = (N + 127) / 128;
    dim3 blk(256);

    // ---- CSR build ----
    hipMemsetAsync(deg, 0, (size_t)2 * N * 4, stream);
    k_cw<<<1, 64, 0, stream>>>(raw_w, cw, 16);
    k_hist<<<gE, blk, 0, stream>>>(src, dst, deg_in, deg_out, E);
    k_scan1<<<NB, blk, 0, stream>>>(deg_in, row_ptr, part, N);
    k_scan2<<<1, blk, 0, stream>>>(part, NB);
    k_scan3<<<(N + 255) / 256, blk, 0, stream>>>(row_ptr, cursor, part, N, E);
    k_scatter<<<gE, blk, 0, stream>>>(src, dst, cursor, col_idx, E);

    // ---- bf16 weight prep for MFMA GEMMs ----
    k_w2bf<<<(256 * 256 + 255) / 256, blk, 0, stream>>>(Ws2, Wt_emb, 256, 256, 512, 0);
    k_w2bf<<<(256 * 256 + 255) / 256, blk, 0, stream>>>(Wn2, Wt_emb, 256, 256, 512, 256);
    k_w2bf<<<(128 * 256 + 255) / 256, blk, 0, stream>>>(Wa1, Wt_a1, 256, 128, 256, 0);

    // ---- node features / layer-1 ----
    k_init<<<g16t, blk, 0, stream>>>(x, cw, deg_out, X32, ns, N);
    k_agg16<<<g16t, blk, 0, stream>>>(x, cw, ns, row_ptr, col_idx, X32, g16, N);
    k_l1<<<dim3(MB, 4), blk, 0, stream>>>(X32, Ws1, Wn1, b1, Wskip, bskip, out1, N);

    // ---- layer 2 (MFMA; emb lives in out_aux region until aux branch runs) ----
    k_m2<<<N, blk, 0, stream>>>(out1, row_ptr, col_idx, m2, N);
    k_gemm_mf<false, true><<<dim3(MBT, 2), blk, 0, stream>>>(out1, m2, Wt_emb, b2,
                                                             out1, emb, 256, N, 512);

    // ---- heads (consume emb before aux overwrites it) ----
    k_scores<<<(N + 3) / 4, blk, 0, stream>>>(emb, Wfc, bfc, scores, N);
    k_primary<<<(P + 255) / 256, blk, 0, stream>>>(scores, pairs, out_primary, P);
    k_gemm_mf<true, false><<<dim3(MBT, 1), blk, 0, stream>>>(emb, nullptr, Wt_a1, ba1,
                                                             nullptr, hid, 128, N, 256);
    k_attn<<<(N + 3) / 4, blk, 0, stream>>>(hid, Wa2, ba2, out_attn, N);

    // ---- auxiliary criteria-relation branch (writes real aux output last) ----
    k_a1<<<g48t, blk, 0, stream>>>(g16, Wg1, bg1, ns, a1n, N);
    k_agg48<<<g48t, blk, 0, stream>>>(a1n, row_ptr, col_idx, g48, N);
    k_gemm<false><<<dim3(MB, 4), blk, 0, stream>>>(g48, nullptr, 48, 48,
                                                   Wg2, nullptr, 256, 48,
                                                   bg2, out_aux, 256, N, 48);
}

// Round 5
// 974.932 us; speedup vs baseline: 1.6554x; 1.2532x over previous
//
#include <hip/hip_runtime.h>
#include <hip/hip_bf16.h>
#include <math.h>

// ---------------------------------------------------------------------------
// GNN model on MI355X. N=100000, E=1600000, IN_F=16, H_F=256, C=16.
//   CSR build -> k_init/k_agg16 -> k_l1 (fused skip+layer1, bf16 out1)
//   -> k_m2 (bf16 mean) -> emb GEMM (bf16 MFMA, K=512, emb in d_out aux
//   region) -> scores/primary + attn GEMM (bf16 MFMA) -> aux branch last.
// R3: emb GEMM VALU-bound fp32 457us -> R4 MFMA (left top-5; total 1222us).
// R4 profile: k_m2 305us, VALU 14%, occ 87%, FETCH 386MB (L2 dup of random
//   gather) -> latency-bound, 2B/lane loads, 1 load in flight.
// R5: gather kernels -> wave-per-node, 8B/lane (k_m2), unroll x4 for MLP.
// ---------------------------------------------------------------------------

#define SCANB 1024

typedef __attribute__((ext_vector_type(8))) short bf16x8;
typedef __attribute__((ext_vector_type(4))) float f32x4;

__device__ __forceinline__ float sigmoidf_(float x) { return 1.0f / (1.0f + expf(-x)); }

__device__ __forceinline__ float bf2f(unsigned short u) {
    union { unsigned int i; float f; } c;
    c.i = ((unsigned int)u) << 16;
    return c.f;
}
__device__ __forceinline__ unsigned short f2bf(float f) {
    union { float f; unsigned int i; } c;
    c.f = f;
    unsigned int x = c.i;
    x += 0x7fffu + ((x >> 16) & 1u);  // round-to-nearest-even
    return (unsigned short)(x >> 16);
}

// softmax over the 16-element criteria weight vector.
__global__ void k_cw(const float* __restrict__ rw, float* __restrict__ cw, int c) {
    if (threadIdx.x == 0 && blockIdx.x == 0) {
        float mx = -1e30f;
        for (int i = 0; i < c; ++i) mx = fmaxf(mx, rw[i]);
        float s = 0.f;
        for (int i = 0; i < c; ++i) s += expf(rw[i] - mx);
        for (int i = 0; i < c; ++i) cw[i] = expf(rw[i] - mx) / s;
    }
}

__global__ void k_hist(const int* __restrict__ src, const int* __restrict__ dst,
                       int* __restrict__ deg_in, int* __restrict__ deg_out, int e) {
    int i = blockIdx.x * blockDim.x + threadIdx.x;
    if (i < e) {
        atomicAdd(&deg_in[dst[i]], 1);
        atomicAdd(&deg_out[src[i]], 1);
    }
}

// Block-local exclusive scan of deg (SCANB elems / 256-thread block).
__global__ void k_scan1(const int* __restrict__ deg, int* __restrict__ local,
                        int* __restrict__ part, int n) {
    __shared__ int sb[256];
    const int tid = threadIdx.x;
    const int i0 = blockIdx.x * SCANB + tid * 4;
    int v[4];
#pragma unroll
    for (int j = 0; j < 4; ++j) v[j] = (i0 + j < n) ? deg[i0 + j] : 0;
    int t = v[0] + v[1] + v[2] + v[3];
    sb[tid] = t;
    __syncthreads();
    for (int off = 1; off < 256; off <<= 1) {
        int x = sb[tid];
        if (tid >= off) x += sb[tid - off];
        __syncthreads();
        sb[tid] = x;
        __syncthreads();
    }
    int incl = sb[tid];
    int ex = incl - t;
    if (tid == 255) part[blockIdx.x] = incl;
    int p = ex;
#pragma unroll
    for (int j = 0; j < 4; ++j) {
        if (i0 + j < n) local[i0 + j] = p;
        p += v[j];
    }
}

__global__ void k_scan2(int* __restrict__ part, int nb) {
    __shared__ int sb[256];
    const int tid = threadIdx.x;
    int t = (tid < nb) ? part[tid] : 0;
    sb[tid] = t;
    __syncthreads();
    for (int off = 1; off < 256; off <<= 1) {
        int x = sb[tid];
        if (tid >= off) x += sb[tid - off];
        __syncthreads();
        sb[tid] = x;
        __syncthreads();
    }
    if (tid < nb) part[tid] = sb[tid] - t;
}

__global__ void k_scan3(int* __restrict__ row_ptr, int* __restrict__ cursor,
                        const int* __restrict__ part, int n, int e) {
    int i = blockIdx.x * blockDim.x + threadIdx.x;
    if (i < n) {
        int v = row_ptr[i] + part[i >> 10];  // SCANB == 1024
        row_ptr[i] = v;
        cursor[i] = v;
    }
    if (i == 0) row_ptr[n] = e;
}

__global__ void k_scatter(const int* __restrict__ src, const int* __restrict__ dst,
                          int* __restrict__ cursor, int* __restrict__ col_idx, int e) {
    int i = blockIdx.x * blockDim.x + threadIdx.x;
    if (i < e) {
        int d = dst[i];
        int p = atomicAdd(&cursor[d], 1);
        col_idx[p] = src[i];
    }
}

// wx into X32[:,0:16]; ns = rsqrt(deg_out) (0 if isolated).
__global__ void k_init(const float* __restrict__ x, const float* __restrict__ cw,
                       const int* __restrict__ deg_out, float* __restrict__ X32,
                       float* __restrict__ ns, int n) {
    int t = blockIdx.x * blockDim.x + threadIdx.x;
    if (t >= n * 16) return;
    int node = t >> 4, f = t & 15;
    float xv = x[t];
    X32[node * 32 + f] = xv * cw[f];
    if (f == 0) {
        int dg = deg_out[node];
        ns[node] = dg > 0 ? rsqrtf((float)dg) : 0.f;
    }
}

// Fused 16-feature aggregation: m1 (SAGE mean of wx) + gcn1 agg.
// One wave per node: 4 neighbor-groups x 16 lanes, unroll x2, shfl reduce.
__global__ void k_agg16(const float* __restrict__ x, const float* __restrict__ cw,
                        const float* __restrict__ ns, const int* __restrict__ row_ptr,
                        const int* __restrict__ col_idx, float* __restrict__ X32,
                        float* __restrict__ g16, int n) {
    int node = blockIdx.x * 4 + (threadIdx.x >> 6);
    int l = threadIdx.x & 63;
    if (node >= n) return;
    const int grp = l >> 4, f = l & 15;
    const int r0 = row_ptr[node], r1 = row_ptr[node + 1];
    float am = 0.f, ah = 0.f;
    int j = r0 + grp;
    for (; j + 4 < r1; j += 8) {
        int s0 = col_idx[j], s1 = col_idx[j + 4];
        float x0 = x[(s0 << 4) + f], x1 = x[(s1 << 4) + f];
        am += x0 + x1;
        ah += x0 * ns[s0] + x1 * ns[s1];
    }
    if (j < r1) {
        int s = col_idx[j];
        float xv = x[(s << 4) + f];
        am += xv;
        ah += xv * ns[s];
    }
    am += __shfl_xor(am, 16); am += __shfl_xor(am, 32);
    ah += __shfl_xor(ah, 16); ah += __shfl_xor(ah, 32);
    if (l < 16) {
        int dg = r1 - r0;
        X32[node * 32 + 16 + f] = cw[f] * am / (float)(dg > 0 ? dg : 1);
        float nd = dg > 0 ? rsqrtf((float)dg) : 0.f;
        g16[node * 16 + f] = ah * nd;
    }
}

// a1n = relu(g16 @ Wg1 + bg1) * ns  (pre-scaled for the next aggregation).
__global__ void k_a1(const float* __restrict__ g16, const float* __restrict__ Wg1,
                     const float* __restrict__ bg1, const float* __restrict__ ns,
                     float* __restrict__ a1n, int n) {
    __shared__ float Wg1s[768];
    __shared__ float bg1s[48];
    for (int q = threadIdx.x; q < 768; q += 256) Wg1s[q] = Wg1[q];
    if (threadIdx.x < 48) bg1s[threadIdx.x] = bg1[threadIdx.x];
    __syncthreads();
    int gid = blockIdx.x * blockDim.x + threadIdx.x;
    if (gid >= n * 48) return;
    int node = gid / 48, c = gid - node * 48;
    float acc = bg1s[c];
    const float* g = &g16[node * 16];
#pragma unroll
    for (int k = 0; k < 16; ++k) acc += g[k] * Wg1s[k * 48 + c];
    a1n[gid] = fmaxf(acc, 0.f) * ns[node];
}

// g48 = sum(a1n[src]) * nd. One wave per node, 48 active lanes, unroll x4.
__global__ void k_agg48(const float* __restrict__ a1n, const int* __restrict__ row_ptr,
                        const int* __restrict__ col_idx, float* __restrict__ g48, int n) {
    int node = blockIdx.x * 4 + (threadIdx.x >> 6);
    int l = threadIdx.x & 63;
    if (node >= n || l >= 48) return;
    const int r0 = row_ptr[node], r1 = row_ptr[node + 1];
    float acc = 0.f;
    int j = r0;
    for (; j + 4 <= r1; j += 4) {
        int s0 = col_idx[j], s1 = col_idx[j + 1], s2 = col_idx[j + 2], s3 = col_idx[j + 3];
        acc += a1n[s0 * 48 + l] + a1n[s1 * 48 + l] + a1n[s2 * 48 + l] + a1n[s3 * 48 + l];
    }
    for (; j < r1; ++j) acc += a1n[col_idx[j] * 48 + l];
    int dg = r1 - r0;
    float nd = dg > 0 ? rsqrtf((float)dg) : 0.f;
    g48[node * 48 + l] = acc * nd;
}

// Fused layer-1: out1 = relu([wx|m1]@[Ws1;Wn1] + b1) + wx@Wskip + bskip (bf16 out).
__launch_bounds__(256)
__global__ void k_l1(const float* __restrict__ X32, const float* __restrict__ Ws1,
                     const float* __restrict__ Wn1, const float* __restrict__ b1,
                     const float* __restrict__ Wskip, const float* __restrict__ bskip,
                     unsigned short* __restrict__ out1, int M) {
    __shared__ __align__(16) float As[32][64];
    __shared__ __align__(16) float Wm[32][64];
    __shared__ __align__(16) float Wk[16][64];
    const int tid = threadIdx.x;
    const int tx = tid & 15, ty = tid >> 4;
    const int row0 = blockIdx.x * 64, col0 = blockIdx.y * 64;
    const int ar = tid >> 2, ac8 = (tid & 3) << 3;
    const int arow = row0 + ar;
    float4 a0 = make_float4(0.f, 0.f, 0.f, 0.f), a1v = a0;
    if (arow < M) {
        a0  = *(const float4*)&X32[arow * 32 + ac8];
        a1v = *(const float4*)&X32[arow * 32 + ac8 + 4];
    }
    const int wkr = tid >> 4, wc4 = (tid & 15) << 2;
    const float4 wm0 = *(const float4*)&Ws1[wkr * 256 + col0 + wc4];
    const float4 wm1 = *(const float4*)&Wn1[wkr * 256 + col0 + wc4];
    const float4 wk0 = *(const float4*)&Wskip[wkr * 256 + col0 + wc4];
    As[ac8 + 0][ar] = a0.x;  As[ac8 + 1][ar] = a0.y;
    As[ac8 + 2][ar] = a0.z;  As[ac8 + 3][ar] = a0.w;
    As[ac8 + 4][ar] = a1v.x; As[ac8 + 5][ar] = a1v.y;
    As[ac8 + 6][ar] = a1v.z; As[ac8 + 7][ar] = a1v.w;
    *(float4*)&Wm[wkr][wc4]      = wm0;
    *(float4*)&Wm[16 + wkr][wc4] = wm1;
    *(float4*)&Wk[wkr][wc4]      = wk0;
    __syncthreads();

    float acc[4][4] = {{0.f}};
    float accs[4][4] = {{0.f}};
#pragma unroll
    for (int kk = 0; kk < 32; ++kk) {
        const float4 a = *(const float4*)&As[kk][tx << 2];
        const float4 w = *(const float4*)&Wm[kk][ty << 2];
        acc[0][0] += a.x * w.x; acc[0][1] += a.x * w.y; acc[0][2] += a.x * w.z; acc[0][3] += a.x * w.w;
        acc[1][0] += a.y * w.x; acc[1][1] += a.y * w.y; acc[1][2] += a.y * w.z; acc[1][3] += a.y * w.w;
        acc[2][0] += a.z * w.x; acc[2][1] += a.z * w.y; acc[2][2] += a.z * w.z; acc[2][3] += a.z * w.w;
        acc[3][0] += a.w * w.x; acc[3][1] += a.w * w.y; acc[3][2] += a.w * w.z; acc[3][3] += a.w * w.w;
    }
#pragma unroll
    for (int kk = 0; kk < 16; ++kk) {
        const float4 a = *(const float4*)&As[kk][tx << 2];
        const float4 w = *(const float4*)&Wk[kk][ty << 2];
        accs[0][0] += a.x * w.x; accs[0][1] += a.x * w.y; accs[0][2] += a.x * w.z; accs[0][3] += a.x * w.w;
        accs[1][0] += a.y * w.x; accs[1][1] += a.y * w.y; accs[1][2] += a.y * w.z; accs[1][3] += a.y * w.w;
        accs[2][0] += a.z * w.x; accs[2][1] += a.z * w.y; accs[2][2] += a.z * w.z; accs[2][3] += a.z * w.w;
        accs[3][0] += a.w * w.x; accs[3][1] += a.w * w.y; accs[3][2] += a.w * w.z; accs[3][3] += a.w * w.w;
    }
    const float4 bm = *(const float4*)&b1[col0 + (ty << 2)];
    const float4 bk = *(const float4*)&bskip[col0 + (ty << 2)];
#pragma unroll
    for (int i = 0; i < 4; ++i) {
        int row = row0 + (tx << 2) + i;
        if (row >= M) continue;
        float v0 = fmaxf(acc[i][0] + bm.x, 0.f) + accs[i][0] + bk.x;
        float v1 = fmaxf(acc[i][1] + bm.y, 0.f) + accs[i][1] + bk.y;
        float v2 = fmaxf(acc[i][2] + bm.z, 0.f) + accs[i][2] + bk.z;
        float v3 = fmaxf(acc[i][3] + bm.w, 0.f) + accs[i][3] + bk.w;
        ushort4 o;
        o.x = f2bf(v0); o.y = f2bf(v1); o.z = f2bf(v2); o.w = f2bf(v3);
        *(ushort4*)&out1[(size_t)row * 256 + col0 + (ty << 2)] = o;
    }
}

// m2 = mean of out1[src] per dst (bf16). One wave per node, 8B/lane, unroll x4.
__global__ void k_m2(const unsigned short* __restrict__ out1, const int* __restrict__ row_ptr,
                     const int* __restrict__ col_idx, unsigned short* __restrict__ m2, int n) {
    int node = blockIdx.x * 4 + (threadIdx.x >> 6);
    int l = threadIdx.x & 63;
    if (node >= n) return;
    const int r0 = row_ptr[node], r1 = row_ptr[node + 1];
    float a0 = 0.f, a1 = 0.f, a2 = 0.f, a3 = 0.f;
    int j = r0;
    for (; j + 4 <= r1; j += 4) {
        int s0 = col_idx[j], s1 = col_idx[j + 1], s2 = col_idx[j + 2], s3 = col_idx[j + 3];
        ushort4 v0 = *(const ushort4*)&out1[(size_t)s0 * 256 + l * 4];
        ushort4 v1 = *(const ushort4*)&out1[(size_t)s1 * 256 + l * 4];
        ushort4 v2 = *(const ushort4*)&out1[(size_t)s2 * 256 + l * 4];
        ushort4 v3 = *(const ushort4*)&out1[(size_t)s3 * 256 + l * 4];
        a0 += bf2f(v0.x) + bf2f(v1.x) + bf2f(v2.x) + bf2f(v3.x);
        a1 += bf2f(v0.y) + bf2f(v1.y) + bf2f(v2.y) + bf2f(v3.y);
        a2 += bf2f(v0.z) + bf2f(v1.z) + bf2f(v2.z) + bf2f(v3.z);
        a3 += bf2f(v0.w) + bf2f(v1.w) + bf2f(v2.w) + bf2f(v3.w);
    }
    for (; j < r1; ++j) {
        ushort4 v = *(const ushort4*)&out1[(size_t)col_idx[j] * 256 + l * 4];
        a0 += bf2f(v.x); a1 += bf2f(v.y); a2 += bf2f(v.z); a3 += bf2f(v.w);
    }
    int dg = r1 - r0;
    float inv = 1.f / (float)(dg > 0 ? dg : 1);
    ushort4 o;
    o.x = f2bf(a0 * inv); o.y = f2bf(a1 * inv);
    o.z = f2bf(a2 * inv); o.w = f2bf(a3 * inv);
    *(ushort4*)&m2[(size_t)node * 256 + l * 4] = o;
}

// Transpose-convert fp32 weight [K,Ncol] -> bf16 K-major [Ncol][ldK] at koff.
__global__ void k_w2bf(const float* __restrict__ W, unsigned short* __restrict__ o,
                       int K, int Ncol, int ldK, int koff) {
    int i = blockIdx.x * blockDim.x + threadIdx.x;
    if (i >= K * Ncol) return;
    int c = i / K, k = i - c * K;
    o[(size_t)c * ldK + koff + k] = f2bf(W[(size_t)k * Ncol + c]);
}

// ---------------------------------------------------------------------------
// bf16 MFMA GEMM: out[M,Nc] = relu(A[M,Ktot] @ B + bias) (+ resid).
// 128x128 tile, BK=32, 4 waves 2x2, 4x4 16x16x32 frags/wave. LDS rows
// padded to 40 ushorts. Frag layout m89-verified.
// ---------------------------------------------------------------------------
template <bool AF32, bool RESID>
__launch_bounds__(256)
__global__ void k_gemm_mf(const void* __restrict__ A1, const void* __restrict__ A2,
                          const unsigned short* __restrict__ Bt,
                          const float* __restrict__ bias,
                          const unsigned short* __restrict__ resid,
                          float* __restrict__ out, int ldo, int M, int Ktot) {
    __shared__ __align__(16) unsigned short As[128][40];
    __shared__ __align__(16) unsigned short Bs[128][40];
    const int tid = threadIdx.x;
    const int lane = tid & 63, wave = tid >> 6;
    const int wr = wave >> 1, wc = wave & 1;
    const int fi = lane & 15, koct = lane >> 4;
    const int srow = tid >> 1, shalf = tid & 1;
    const int row0 = blockIdx.x * 128, col0 = blockIdx.y * 128;
    const int arow = row0 + srow;

    f32x4 acc[4][4];
#pragma unroll
    for (int r = 0; r < 4; ++r)
#pragma unroll
        for (int c = 0; c < 4; ++c) acc[r][c] = (f32x4){0.f, 0.f, 0.f, 0.f};

    for (int k0 = 0; k0 < Ktot; k0 += 32) {
        uint4 a0 = {0, 0, 0, 0}, a1 = {0, 0, 0, 0};
        if (AF32) {
            if (arow < M) {
                const float* Af = (const float*)A1;
                const size_t p = (size_t)arow * Ktot + k0 + shalf * 16;
                const float4 f0 = *(const float4*)&Af[p + 0];
                const float4 f1 = *(const float4*)&Af[p + 4];
                const float4 f2 = *(const float4*)&Af[p + 8];
                const float4 f3 = *(const float4*)&Af[p + 12];
                union { uint4 v[2]; unsigned short s[16]; } pk;
                pk.s[0] = f2bf(f0.x);  pk.s[1] = f2bf(f0.y);
                pk.s[2] = f2bf(f0.z);  pk.s[3] = f2bf(f0.w);
                pk.s[4] = f2bf(f1.x);  pk.s[5] = f2bf(f1.y);
                pk.s[6] = f2bf(f1.z);  pk.s[7] = f2bf(f1.w);
                pk.s[8] = f2bf(f2.x);  pk.s[9] = f2bf(f2.y);
                pk.s[10] = f2bf(f2.z); pk.s[11] = f2bf(f2.w);
                pk.s[12] = f2bf(f3.x); pk.s[13] = f2bf(f3.y);
                pk.s[14] = f2bf(f3.z); pk.s[15] = f2bf(f3.w);
                a0 = pk.v[0]; a1 = pk.v[1];
            }
        } else {
            const unsigned short* Ap = (const unsigned short*)((k0 < 256) ? A1 : A2);
            const int ka = k0 & 255;
            if (arow < M) {
                const size_t p = (size_t)arow * 256 + ka + shalf * 16;
                a0 = *(const uint4*)&Ap[p];
                a1 = *(const uint4*)&Ap[p + 8];
            }
        }
        const size_t pb = (size_t)(col0 + srow) * Ktot + k0 + shalf * 16;
        const uint4 b0 = *(const uint4*)&Bt[pb];
        const uint4 b1 = *(const uint4*)&Bt[pb + 8];
        __syncthreads();
        *(uint4*)&As[srow][shalf * 16 + 0] = a0;
        *(uint4*)&As[srow][shalf * 16 + 8] = a1;
        *(uint4*)&Bs[srow][shalf * 16 + 0] = b0;
        *(uint4*)&Bs[srow][shalf * 16 + 8] = b1;
        __syncthreads();
        bf16x8 af[4], bf[4];
#pragma unroll
        for (int r = 0; r < 4; ++r)
            af[r] = *(const bf16x8*)&As[wr * 64 + r * 16 + fi][koct * 8];
#pragma unroll
        for (int c = 0; c < 4; ++c)
            bf[c] = *(const bf16x8*)&Bs[wc * 64 + c * 16 + fi][koct * 8];
#pragma unroll
        for (int r = 0; r < 4; ++r)
#pragma unroll
            for (int c = 0; c < 4; ++c)
                acc[r][c] = __builtin_amdgcn_mfma_f32_16x16x32_bf16(af[r], bf[c], acc[r][c], 0, 0, 0);
    }

#pragma unroll
    for (int r = 0; r < 4; ++r) {
        const int rowb = row0 + wr * 64 + r * 16 + koct * 4;
#pragma unroll
        for (int c = 0; c < 4; ++c) {
            const int col = col0 + wc * 64 + c * 16 + fi;
            const float bv = bias[col];
#pragma unroll
            for (int q = 0; q < 4; ++q) {
                const int rr = rowb + q;
                if (rr >= M) continue;
                float v = fmaxf(acc[r][c][q] + bv, 0.f);
                if (RESID) v += bf2f(resid[(size_t)rr * 256 + col]);
                out[(size_t)rr * ldo + col] = v;
            }
        }
    }
}

// ---------------------------------------------------------------------------
// fp32 tiled GEMM (64x64 tile, BK=16, 4x4 micro-tile) — used for aux (K=48).
// ---------------------------------------------------------------------------
template <bool RELU>
__launch_bounds__(256)
__global__ void k_gemm(const float* __restrict__ A, const float* __restrict__ A2, int lda, int ksA,
                       const float* __restrict__ W, const float* __restrict__ W2, int ldw, int ksW,
                       const float* __restrict__ bias, float* __restrict__ out, int ldo,
                       int M, int K) {
    __shared__ __align__(16) float As[16][64];
    __shared__ __align__(16) float Ws[16][64];
    const int tid = threadIdx.x;
    const int tx = tid & 15, ty = tid >> 4;
    const int row0 = blockIdx.x * 64, col0 = blockIdx.y * 64;
    const int ar = tid >> 2, ac4 = (tid & 3) << 2;
    const int wk = tid >> 4, wc4 = (tid & 15) << 2;
    const int arow = row0 + ar;

    float acc[4][4] = {{0.f}};

    for (int k0 = 0; k0 < K; k0 += 16) {
        const float* Ap; int ka;
        if (k0 < ksA) { Ap = A; ka = k0; } else { Ap = A2; ka = k0 - ksA; }
        const float* Wp; int kw;
        if (k0 < ksW) { Wp = W; kw = k0; } else { Wp = W2; kw = k0 - ksW; }
        float4 av = make_float4(0.f, 0.f, 0.f, 0.f);
        if (arow < M) av = *(const float4*)&Ap[(size_t)arow * lda + ka + ac4];
        float4 wv = *(const float4*)&Wp[(size_t)(kw + wk) * ldw + col0 + wc4];
        __syncthreads();
        As[ac4 + 0][ar] = av.x; As[ac4 + 1][ar] = av.y;
        As[ac4 + 2][ar] = av.z; As[ac4 + 3][ar] = av.w;
        *(float4*)&Ws[wk][wc4] = wv;
        __syncthreads();
#pragma unroll
        for (int kk = 0; kk < 16; ++kk) {
            const float4 a = *(const float4*)&As[kk][tx << 2];
            const float4 w = *(const float4*)&Ws[kk][ty << 2];
            acc[0][0] += a.x * w.x; acc[0][1] += a.x * w.y; acc[0][2] += a.x * w.z; acc[0][3] += a.x * w.w;
            acc[1][0] += a.y * w.x; acc[1][1] += a.y * w.y; acc[1][2] += a.y * w.z; acc[1][3] += a.y * w.w;
            acc[2][0] += a.z * w.x; acc[2][1] += a.z * w.y; acc[2][2] += a.z * w.z; acc[2][3] += a.z * w.w;
            acc[3][0] += a.w * w.x; acc[3][1] += a.w * w.y; acc[3][2] += a.w * w.z; acc[3][3] += a.w * w.w;
        }
    }
    float4 bv = make_float4(0.f, 0.f, 0.f, 0.f);
    if (bias) bv = *(const float4*)&bias[col0 + (ty << 2)];
#pragma unroll
    for (int i = 0; i < 4; ++i) {
        int row = row0 + (tx << 2) + i;
        if (row >= M) continue;
        float4 v;
        v.x = acc[i][0] + bv.x; v.y = acc[i][1] + bv.y;
        v.z = acc[i][2] + bv.z; v.w = acc[i][3] + bv.w;
        if (RELU) {
            v.x = fmaxf(v.x, 0.f); v.y = fmaxf(v.y, 0.f);
            v.z = fmaxf(v.z, 0.f); v.w = fmaxf(v.w, 0.f);
        }
        *(float4*)&out[(size_t)row * ldo + col0 + (ty << 2)] = v;
    }
}

// scores[n] = emb[n,:] . Wfc + bfc  — one wave per node.
__global__ void k_scores(const float* __restrict__ emb, const float* __restrict__ Wfc,
                         const float* __restrict__ bfc, float* __restrict__ scores, int n) {
    int node = blockIdx.x * 4 + (threadIdx.x >> 6);
    int l = threadIdx.x & 63;
    if (node >= n) return;
    const float4 e = *(const float4*)&emb[(size_t)node * 256 + l * 4];
    const float4 w = *(const float4*)&Wfc[l * 4];
    float p = e.x * w.x + e.y * w.y + e.z * w.z + e.w * w.w;
    for (int off = 32; off > 0; off >>= 1) p += __shfl_down(p, off);
    if (l == 0) scores[node] = p + bfc[0];
}

__global__ void k_primary(const float* __restrict__ scores, const int* __restrict__ pairs,
                          float* __restrict__ out, int p) {
    int i = blockIdx.x * blockDim.x + threadIdx.x;
    if (i < p) {
        int a = pairs[2 * i], b = pairs[2 * i + 1];
        out[i] = sigmoidf_(scores[a] - scores[b]);
    }
}

// attn[n] = sigmoid(hid[n,:] . Wa2 + ba2) — one wave per node (128 feats).
__global__ void k_attn(const float* __restrict__ hid, const float* __restrict__ Wa2,
                       const float* __restrict__ ba2, float* __restrict__ out, int n) {
    int node = blockIdx.x * 4 + (threadIdx.x >> 6);
    int l = threadIdx.x & 63;
    if (node >= n) return;
    const float2 h = *(const float2*)&hid[(size_t)node * 128 + l * 2];
    const float2 w = *(const float2*)&Wa2[l * 2];
    float p = h.x * w.x + h.y * w.y;
    for (int off = 32; off > 0; off >>= 1) p += __shfl_down(p, off);
    if (l == 0) out[node] = sigmoidf_(p + ba2[0]);
}

extern "C" void kernel_launch(void* const* d_in, const int* in_sizes, int n_in,
                              void* d_out, int out_size, void* d_ws, size_t ws_size,
                              hipStream_t stream) {
    const float* x     = (const float*)d_in[0];
    const int*   src   = (const int*)d_in[1];
    const int*   dst   = (const int*)d_in[2];
    const int*   pairs = (const int*)d_in[3];
    const float* raw_w = (const float*)d_in[4];
    const float* Ws1   = (const float*)d_in[5];
    const float* Wn1   = (const float*)d_in[6];
    const float* b1    = (const float*)d_in[7];
    const float* Ws2   = (const float*)d_in[8];
    const float* Wn2   = (const float*)d_in[9];
    const float* b2    = (const float*)d_in[10];
    const float* Wskip = (const float*)d_in[11];
    const float* bskip = (const float*)d_in[12];
    const float* Wg1   = (const float*)d_in[13];
    const float* bg1   = (const float*)d_in[14];
    const float* Wg2   = (const float*)d_in[15];
    const float* bg2   = (const float*)d_in[16];
    const float* Wfc   = (const float*)d_in[17];
    const float* bfc   = (const float*)d_in[18];
    const float* Wa1   = (const float*)d_in[19];
    const float* ba1   = (const float*)d_in[20];
    const float* Wa2   = (const float*)d_in[21];
    const float* ba2   = (const float*)d_in[22];

    const int N = in_sizes[0] / 16;
    const int E = in_sizes[1];
    const int P = in_sizes[3] / 2;

    // ---- workspace layout (~130 MB total) ----
    char* base = (char*)d_ws;
    size_t off = 0;
    auto alloc = [&](size_t bytes) -> char* {
        char* p = base + off;
        off = (off + bytes + 255) & ~(size_t)255;
        return p;
    };
    float* cw      = (float*)alloc(16 * 4);
    float* ns      = (float*)alloc((size_t)N * 4);
    float* scores  = (float*)alloc((size_t)N * 4);
    int*   deg     = (int*)alloc((size_t)2 * N * 4);
    int*   deg_in  = deg;
    int*   deg_out = deg + N;
    int*   row_ptr = (int*)alloc((size_t)(N + 1) * 4);
    int*   part    = (int*)alloc(256 * 4);
    int*   col_idx = (int*)alloc((size_t)E * 4);
    float* X32     = (float*)alloc((size_t)N * 32 * 4);
    float* g16     = (float*)alloc((size_t)N * 16 * 4);
    unsigned short* Wt_emb = (unsigned short*)alloc(256 * 512 * 2);  // [256 cols][512 k]
    unsigned short* Wt_a1  = (unsigned short*)alloc(128 * 256 * 2);  // [128 cols][256 k]
    char*  bigA    = alloc((size_t)N * 256 * 2);   // out1(bf16) -> hid(f32 N*128)
    char*  bigB    = alloc((size_t)N * 256 * 2);   // m2(bf16)  -> a1n+g48 (f32)
    if (off > ws_size) return;  // ws too small: output stays zero (visible failure)

    int* cursor = deg_in;  // deg_in dead after scan1; reuse as scatter cursor

    unsigned short* out1 = (unsigned short*)bigA;
    float*          hid  = (float*)bigA;
    unsigned short* m2   = (unsigned short*)bigB;
    float*          a1n  = (float*)bigB;
    float*          g48  = (float*)(bigB + (size_t)N * 48 * 4);

    float* out         = (float*)d_out;
    float* out_primary = out;
    float* out_aux     = out + P;            // also doubles as emb scratch
    float* out_attn    = out + P + (size_t)N * 256;
    float* emb         = out_aux;

    const int gE   = (E + 255) / 256;
    const int NB   = (N + SCANB - 1) / SCANB;
    const int g16t = (N * 16 + 255) / 256;
    const int g48t = (N * 48 + 255) / 256;
    const int MB   = (N + 63) / 64;
    const int MBT  = (N + 127) / 128;
    const int NW4  = (N + 3) / 4;   // wave-per-node kernels
    dim3 blk(256);

    // ---- CSR build ----
    hipMemsetAsync(deg, 0, (size_t)2 * N * 4, stream);
    k_cw<<<1, 64, 0, stream>>>(raw_w, cw, 16);
    k_hist<<<gE, blk, 0, stream>>>(src, dst, deg_in, deg_out, E);
    k_scan1<<<NB, blk, 0, stream>>>(deg_in, row_ptr, part, N);
    k_scan2<<<1, blk, 0, stream>>>(part, NB);
    k_scan3<<<(N + 255) / 256, blk, 0, stream>>>(row_ptr, cursor, part, N, E);
    k_scatter<<<gE, blk, 0, stream>>>(src, dst, cursor, col_idx, E);

    // ---- bf16 weight prep for MFMA GEMMs ----
    k_w2bf<<<(256 * 256 + 255) / 256, blk, 0, stream>>>(Ws2, Wt_emb, 256, 256, 512, 0);
    k_w2bf<<<(256 * 256 + 255) / 256, blk, 0, stream>>>(Wn2, Wt_emb, 256, 256, 512, 256);
    k_w2bf<<<(128 * 256 + 255) / 256, blk, 0, stream>>>(Wa1, Wt_a1, 256, 128, 256, 0);

    // ---- node features / layer-1 ----
    k_init<<<g16t, blk, 0, stream>>>(x, cw, deg_out, X32, ns, N);
    k_agg16<<<NW4, blk, 0, stream>>>(x, cw, ns, row_ptr, col_idx, X32, g16, N);
    k_l1<<<dim3(MB, 4), blk, 0, stream>>>(X32, Ws1, Wn1, b1, Wskip, bskip, out1, N);

    // ---- layer 2 (MFMA; emb lives in out_aux region until aux branch runs) ----
    k_m2<<<NW4, blk, 0, stream>>>(out1, row_ptr, col_idx, m2, N);
    k_gemm_mf<false, true><<<dim3(MBT, 2), blk, 0, stream>>>(out1, m2, Wt_emb, b2,
                                                             out1, emb, 256, N, 512);

    // ---- heads (consume emb before aux overwrites it) ----
    k_scores<<<NW4, blk, 0, stream>>>(emb, Wfc, bfc, scores, N);
    k_primary<<<(P + 255) / 256, blk, 0, stream>>>(scores, pairs, out_primary, P);
    k_gemm_mf<true, false><<<dim3(MBT, 1), blk, 0, stream>>>(emb, nullptr, Wt_a1, ba1,
                                                             nullptr, hid, 128, N, 256);
    k_attn<<<NW4, blk, 0, stream>>>(hid, Wa2, ba2, out_attn, N);

    // ---- auxiliary criteria-relation branch (writes real aux output last) ----
    k_a1<<<g48t, blk, 0, stream>>>(g16, Wg1, bg1, ns, a1n, N);
    k_agg48<<<NW4, blk, 0, stream>>>(a1n, row_ptr, col_idx, g48, N);
    k_gemm<false><<<dim3(MB, 4), blk, 0, stream>>>(g48, nullptr, 48, 48,
                                                   Wg2, nullptr, 256, 48,
                                                   bg2, out_aux, 256, N, 48);
}

// Round 6
// 890.505 us; speedup vs baseline: 1.8123x; 1.0948x over previous
//
#include <hip/hip_runtime.h>
#include <hip/hip_bf16.h>
#include <math.h>

// ---------------------------------------------------------------------------
// GNN model on MI355X. N=100000, E=1600000, IN_F=16, H_F=256, C=16.
// R3: emb GEMM VALU-bound fp32 457us -> R4 MFMA (total 1222us).
// R4: k_m2 latency-bound 305us -> R5 wave-per-node gathers (total 975us).
// R5 profile: k_scatter 130us, WRITE_SIZE 105MB vs 6.4MB logical (random
//   4B stores -> full-line writebacks, zero combining).
// R6: (a) dst-range-bucketed scatter, 8 groups keyed to blockIdx&7 (XCD
//   round-robin) -> write combining in one L2; (b) scores fused into emb
//   GEMM epilogue (bfc cancels in the pairwise diff; k_scores removed).
// ---------------------------------------------------------------------------

#define SCANB 1024

typedef __attribute__((ext_vector_type(8))) short bf16x8;
typedef __attribute__((ext_vector_type(4))) float f32x4;

__device__ __forceinline__ float sigmoidf_(float x) { return 1.0f / (1.0f + expf(-x)); }

__device__ __forceinline__ float bf2f(unsigned short u) {
    union { unsigned int i; float f; } c;
    c.i = ((unsigned int)u) << 16;
    return c.f;
}
__device__ __forceinline__ unsigned short f2bf(float f) {
    union { float f; unsigned int i; } c;
    c.f = f;
    unsigned int x = c.i;
    x += 0x7fffu + ((x >> 16) & 1u);  // round-to-nearest-even
    return (unsigned short)(x >> 16);
}

// softmax over the 16-element criteria weight vector.
__global__ void k_cw(const float* __restrict__ rw, float* __restrict__ cw, int c) {
    if (threadIdx.x == 0 && blockIdx.x == 0) {
        float mx = -1e30f;
        for (int i = 0; i < c; ++i) mx = fmaxf(mx, rw[i]);
        float s = 0.f;
        for (int i = 0; i < c; ++i) s += expf(rw[i] - mx);
        for (int i = 0; i < c; ++i) cw[i] = expf(rw[i] - mx) / s;
    }
}

__global__ void k_hist(const int* __restrict__ src, const int* __restrict__ dst,
                       int* __restrict__ deg_in, int* __restrict__ deg_out, int e) {
    int i = blockIdx.x * blockDim.x + threadIdx.x;
    if (i < e) {
        atomicAdd(&deg_in[dst[i]], 1);
        atomicAdd(&deg_out[src[i]], 1);
    }
}

// Block-local exclusive scan of deg (SCANB elems / 256-thread block).
__global__ void k_scan1(const int* __restrict__ deg, int* __restrict__ local,
                        int* __restrict__ part, int n) {
    __shared__ int sb[256];
    const int tid = threadIdx.x;
    const int i0 = blockIdx.x * SCANB + tid * 4;
    int v[4];
#pragma unroll
    for (int j = 0; j < 4; ++j) v[j] = (i0 + j < n) ? deg[i0 + j] : 0;
    int t = v[0] + v[1] + v[2] + v[3];
    sb[tid] = t;
    __syncthreads();
    for (int off = 1; off < 256; off <<= 1) {
        int x = sb[tid];
        if (tid >= off) x += sb[tid - off];
        __syncthreads();
        sb[tid] = x;
        __syncthreads();
    }
    int incl = sb[tid];
    int ex = incl - t;
    if (tid == 255) part[blockIdx.x] = incl;
    int p = ex;
#pragma unroll
    for (int j = 0; j < 4; ++j) {
        if (i0 + j < n) local[i0 + j] = p;
        p += v[j];
    }
}

__global__ void k_scan2(int* __restrict__ part, int nb) {
    __shared__ int sb[256];
    const int tid = threadIdx.x;
    int t = (tid < nb) ? part[tid] : 0;
    sb[tid] = t;
    __syncthreads();
    for (int off = 1; off < 256; off <<= 1) {
        int x = sb[tid];
        if (tid >= off) x += sb[tid - off];
        __syncthreads();
        sb[tid] = x;
        __syncthreads();
    }
    if (tid < nb) part[tid] = sb[tid] - t;
}

__global__ void k_scan3(int* __restrict__ row_ptr, int* __restrict__ cursor,
                        const int* __restrict__ part, int n, int e) {
    int i = blockIdx.x * blockDim.x + threadIdx.x;
    if (i < n) {
        int v = row_ptr[i] + part[i >> 10];  // SCANB == 1024
        row_ptr[i] = v;
        cursor[i] = v;
    }
    if (i == 0) row_ptr[n] = e;
}

// dst-range-bucketed scatter. Group r = blockIdx&7 (round-robin -> XCD r)
// handles dst in [r*rng, r*rng+rng): all col_idx writes for a range come
// from one XCD's L2 in one window -> full-line write combining. Each group
// re-reads the whole edge list (L3-resident, cheap).
__global__ void k_scatter8(const int* __restrict__ src, const int* __restrict__ dst,
                           int* __restrict__ cursor, int* __restrict__ col_idx,
                           int e, int n, int rng) {
    const int r = blockIdx.x & 7;
    const int lo = r * rng;
    const int hi = min(n, lo + rng);
    const int nb = gridDim.x >> 3;
    const int bi = blockIdx.x >> 3;
    const int stride = nb * blockDim.x;
    for (int i = bi * blockDim.x + threadIdx.x; i < e; i += stride) {
        int d = dst[i];
        if (d >= lo && d < hi) {
            int p = atomicAdd(&cursor[d], 1);
            col_idx[p] = src[i];
        }
    }
}

// wx into X32[:,0:16]; ns = rsqrt(deg_out) (0 if isolated).
__global__ void k_init(const float* __restrict__ x, const float* __restrict__ cw,
                       const int* __restrict__ deg_out, float* __restrict__ X32,
                       float* __restrict__ ns, int n) {
    int t = blockIdx.x * blockDim.x + threadIdx.x;
    if (t >= n * 16) return;
    int node = t >> 4, f = t & 15;
    float xv = x[t];
    X32[node * 32 + f] = xv * cw[f];
    if (f == 0) {
        int dg = deg_out[node];
        ns[node] = dg > 0 ? rsqrtf((float)dg) : 0.f;
    }
}

// Fused 16-feature aggregation: m1 (SAGE mean of wx) + gcn1 agg.
// One wave per node: 4 neighbor-groups x 16 lanes, unroll x2, shfl reduce.
__global__ void k_agg16(const float* __restrict__ x, const float* __restrict__ cw,
                        const float* __restrict__ ns, const int* __restrict__ row_ptr,
                        const int* __restrict__ col_idx, float* __restrict__ X32,
                        float* __restrict__ g16, int n) {
    int node = blockIdx.x * 4 + (threadIdx.x >> 6);
    int l = threadIdx.x & 63;
    if (node >= n) return;
    const int grp = l >> 4, f = l & 15;
    const int r0 = row_ptr[node], r1 = row_ptr[node + 1];
    float am = 0.f, ah = 0.f;
    int j = r0 + grp;
    for (; j + 4 < r1; j += 8) {
        int s0 = col_idx[j], s1 = col_idx[j + 4];
        float x0 = x[(s0 << 4) + f], x1 = x[(s1 << 4) + f];
        am += x0 + x1;
        ah += x0 * ns[s0] + x1 * ns[s1];
    }
    if (j < r1) {
        int s = col_idx[j];
        float xv = x[(s << 4) + f];
        am += xv;
        ah += xv * ns[s];
    }
    am += __shfl_xor(am, 16); am += __shfl_xor(am, 32);
    ah += __shfl_xor(ah, 16); ah += __shfl_xor(ah, 32);
    if (l < 16) {
        int dg = r1 - r0;
        X32[node * 32 + 16 + f] = cw[f] * am / (float)(dg > 0 ? dg : 1);
        float nd = dg > 0 ? rsqrtf((float)dg) : 0.f;
        g16[node * 16 + f] = ah * nd;
    }
}

// a1n = relu(g16 @ Wg1 + bg1) * ns  (pre-scaled for the next aggregation).
__global__ void k_a1(const float* __restrict__ g16, const float* __restrict__ Wg1,
                     const float* __restrict__ bg1, const float* __restrict__ ns,
                     float* __restrict__ a1n, int n) {
    __shared__ float Wg1s[768];
    __shared__ float bg1s[48];
    for (int q = threadIdx.x; q < 768; q += 256) Wg1s[q] = Wg1[q];
    if (threadIdx.x < 48) bg1s[threadIdx.x] = bg1[threadIdx.x];
    __syncthreads();
    int gid = blockIdx.x * blockDim.x + threadIdx.x;
    if (gid >= n * 48) return;
    int node = gid / 48, c = gid - node * 48;
    float acc = bg1s[c];
    const float* g = &g16[node * 16];
#pragma unroll
    for (int k = 0; k < 16; ++k) acc += g[k] * Wg1s[k * 48 + c];
    a1n[gid] = fmaxf(acc, 0.f) * ns[node];
}

// g48 = sum(a1n[src]) * nd. One wave per node, 48 active lanes, unroll x4.
__global__ void k_agg48(const float* __restrict__ a1n, const int* __restrict__ row_ptr,
                        const int* __restrict__ col_idx, float* __restrict__ g48, int n) {
    int node = blockIdx.x * 4 + (threadIdx.x >> 6);
    int l = threadIdx.x & 63;
    if (node >= n || l >= 48) return;
    const int r0 = row_ptr[node], r1 = row_ptr[node + 1];
    float acc = 0.f;
    int j = r0;
    for (; j + 4 <= r1; j += 4) {
        int s0 = col_idx[j], s1 = col_idx[j + 1], s2 = col_idx[j + 2], s3 = col_idx[j + 3];
        acc += a1n[s0 * 48 + l] + a1n[s1 * 48 + l] + a1n[s2 * 48 + l] + a1n[s3 * 48 + l];
    }
    for (; j < r1; ++j) acc += a1n[col_idx[j] * 48 + l];
    int dg = r1 - r0;
    float nd = dg > 0 ? rsqrtf((float)dg) : 0.f;
    g48[node * 48 + l] = acc * nd;
}

// Fused layer-1: out1 = relu([wx|m1]@[Ws1;Wn1] + b1) + wx@Wskip + bskip (bf16 out).
__launch_bounds__(256)
__global__ void k_l1(const float* __restrict__ X32, const float* __restrict__ Ws1,
                     const float* __restrict__ Wn1, const float* __restrict__ b1,
                     const float* __restrict__ Wskip, const float* __restrict__ bskip,
                     unsigned short* __restrict__ out1, int M) {
    __shared__ __align__(16) float As[32][64];
    __shared__ __align__(16) float Wm[32][64];
    __shared__ __align__(16) float Wk[16][64];
    const int tid = threadIdx.x;
    const int tx = tid & 15, ty = tid >> 4;
    const int row0 = blockIdx.x * 64, col0 = blockIdx.y * 64;
    const int ar = tid >> 2, ac8 = (tid & 3) << 3;
    const int arow = row0 + ar;
    float4 a0 = make_float4(0.f, 0.f, 0.f, 0.f), a1v = a0;
    if (arow < M) {
        a0  = *(const float4*)&X32[arow * 32 + ac8];
        a1v = *(const float4*)&X32[arow * 32 + ac8 + 4];
    }
    const int wkr = tid >> 4, wc4 = (tid & 15) << 2;
    const float4 wm0 = *(const float4*)&Ws1[wkr * 256 + col0 + wc4];
    const float4 wm1 = *(const float4*)&Wn1[wkr * 256 + col0 + wc4];
    const float4 wk0 = *(const float4*)&Wskip[wkr * 256 + col0 + wc4];
    As[ac8 + 0][ar] = a0.x;  As[ac8 + 1][ar] = a0.y;
    As[ac8 + 2][ar] = a0.z;  As[ac8 + 3][ar] = a0.w;
    As[ac8 + 4][ar] = a1v.x; As[ac8 + 5][ar] = a1v.y;
    As[ac8 + 6][ar] = a1v.z; As[ac8 + 7][ar] = a1v.w;
    *(float4*)&Wm[wkr][wc4]      = wm0;
    *(float4*)&Wm[16 + wkr][wc4] = wm1;
    *(float4*)&Wk[wkr][wc4]      = wk0;
    __syncthreads();

    float acc[4][4] = {{0.f}};
    float accs[4][4] = {{0.f}};
#pragma unroll
    for (int kk = 0; kk < 32; ++kk) {
        const float4 a = *(const float4*)&As[kk][tx << 2];
        const float4 w = *(const float4*)&Wm[kk][ty << 2];
        acc[0][0] += a.x * w.x; acc[0][1] += a.x * w.y; acc[0][2] += a.x * w.z; acc[0][3] += a.x * w.w;
        acc[1][0] += a.y * w.x; acc[1][1] += a.y * w.y; acc[1][2] += a.y * w.z; acc[1][3] += a.y * w.w;
        acc[2][0] += a.z * w.x; acc[2][1] += a.z * w.y; acc[2][2] += a.z * w.z; acc[2][3] += a.z * w.w;
        acc[3][0] += a.w * w.x; acc[3][1] += a.w * w.y; acc[3][2] += a.w * w.z; acc[3][3] += a.w * w.w;
    }
#pragma unroll
    for (int kk = 0; kk < 16; ++kk) {
        const float4 a = *(const float4*)&As[kk][tx << 2];
        const float4 w = *(const float4*)&Wk[kk][ty << 2];
        accs[0][0] += a.x * w.x; accs[0][1] += a.x * w.y; accs[0][2] += a.x * w.z; accs[0][3] += a.x * w.w;
        accs[1][0] += a.y * w.x; accs[1][1] += a.y * w.y; accs[1][2] += a.y * w.z; accs[1][3] += a.y * w.w;
        accs[2][0] += a.z * w.x; accs[2][1] += a.z * w.y; accs[2][2] += a.z * w.z; accs[2][3] += a.z * w.w;
        accs[3][0] += a.w * w.x; accs[3][1] += a.w * w.y; accs[3][2] += a.w * w.z; accs[3][3] += a.w * w.w;
    }
    const float4 bm = *(const float4*)&b1[col0 + (ty << 2)];
    const float4 bk = *(const float4*)&bskip[col0 + (ty << 2)];
#pragma unroll
    for (int i = 0; i < 4; ++i) {
        int row = row0 + (tx << 2) + i;
        if (row >= M) continue;
        float v0 = fmaxf(acc[i][0] + bm.x, 0.f) + accs[i][0] + bk.x;
        float v1 = fmaxf(acc[i][1] + bm.y, 0.f) + accs[i][1] + bk.y;
        float v2 = fmaxf(acc[i][2] + bm.z, 0.f) + accs[i][2] + bk.z;
        float v3 = fmaxf(acc[i][3] + bm.w, 0.f) + accs[i][3] + bk.w;
        ushort4 o;
        o.x = f2bf(v0); o.y = f2bf(v1); o.z = f2bf(v2); o.w = f2bf(v3);
        *(ushort4*)&out1[(size_t)row * 256 + col0 + (ty << 2)] = o;
    }
}

// m2 = mean of out1[src] per dst (bf16). One wave per node, 8B/lane, unroll x4.
__global__ void k_m2(const unsigned short* __restrict__ out1, const int* __restrict__ row_ptr,
                     const int* __restrict__ col_idx, unsigned short* __restrict__ m2, int n) {
    int node = blockIdx.x * 4 + (threadIdx.x >> 6);
    int l = threadIdx.x & 63;
    if (node >= n) return;
    const int r0 = row_ptr[node], r1 = row_ptr[node + 1];
    float a0 = 0.f, a1 = 0.f, a2 = 0.f, a3 = 0.f;
    int j = r0;
    for (; j + 4 <= r1; j += 4) {
        int s0 = col_idx[j], s1 = col_idx[j + 1], s2 = col_idx[j + 2], s3 = col_idx[j + 3];
        ushort4 v0 = *(const ushort4*)&out1[(size_t)s0 * 256 + l * 4];
        ushort4 v1 = *(const ushort4*)&out1[(size_t)s1 * 256 + l * 4];
        ushort4 v2 = *(const ushort4*)&out1[(size_t)s2 * 256 + l * 4];
        ushort4 v3 = *(const ushort4*)&out1[(size_t)s3 * 256 + l * 4];
        a0 += bf2f(v0.x) + bf2f(v1.x) + bf2f(v2.x) + bf2f(v3.x);
        a1 += bf2f(v0.y) + bf2f(v1.y) + bf2f(v2.y) + bf2f(v3.y);
        a2 += bf2f(v0.z) + bf2f(v1.z) + bf2f(v2.z) + bf2f(v3.z);
        a3 += bf2f(v0.w) + bf2f(v1.w) + bf2f(v2.w) + bf2f(v3.w);
    }
    for (; j < r1; ++j) {
        ushort4 v = *(const ushort4*)&out1[(size_t)col_idx[j] * 256 + l * 4];
        a0 += bf2f(v.x); a1 += bf2f(v.y); a2 += bf2f(v.z); a3 += bf2f(v.w);
    }
    int dg = r1 - r0;
    float inv = 1.f / (float)(dg > 0 ? dg : 1);
    ushort4 o;
    o.x = f2bf(a0 * inv); o.y = f2bf(a1 * inv);
    o.z = f2bf(a2 * inv); o.w = f2bf(a3 * inv);
    *(ushort4*)&m2[(size_t)node * 256 + l * 4] = o;
}

// Transpose-convert fp32 weight [K,Ncol] -> bf16 K-major [Ncol][ldK] at koff.
__global__ void k_w2bf(const float* __restrict__ W, unsigned short* __restrict__ o,
                       int K, int Ncol, int ldK, int koff) {
    int i = blockIdx.x * blockDim.x + threadIdx.x;
    if (i >= K * Ncol) return;
    int c = i / K, k = i - c * K;
    o[(size_t)c * ldK + koff + k] = f2bf(W[(size_t)k * Ncol + c]);
}

// ---------------------------------------------------------------------------
// bf16 MFMA GEMM: out[M,Nc] = relu(A[M,Ktot] @ B + bias) (+ resid)
// (+ fused scores atomics: scores[row] += sum_col out[row][col]*Wfc[col]).
// 128x128 tile, BK=32, 4 waves 2x2, 4x4 16x16x32 frags/wave. LDS rows
// padded to 40 ushorts. Frag layout m89-verified.
// ---------------------------------------------------------------------------
template <bool AF32, bool RESID, bool SCORES>
__launch_bounds__(256)
__global__ void k_gemm_mf(const void* __restrict__ A1, const void* __restrict__ A2,
                          const unsigned short* __restrict__ Bt,
                          const float* __restrict__ bias,
                          const unsigned short* __restrict__ resid,
                          const float* __restrict__ Wfc, float* __restrict__ scores_out,
                          float* __restrict__ out, int ldo, int M, int Ktot) {
    __shared__ __align__(16) unsigned short As[128][40];
    __shared__ __align__(16) unsigned short Bs[128][40];
    const int tid = threadIdx.x;
    const int lane = tid & 63, wave = tid >> 6;
    const int wr = wave >> 1, wc = wave & 1;
    const int fi = lane & 15, koct = lane >> 4;
    const int srow = tid >> 1, shalf = tid & 1;
    const int row0 = blockIdx.x * 128, col0 = blockIdx.y * 128;
    const int arow = row0 + srow;

    f32x4 acc[4][4];
#pragma unroll
    for (int r = 0; r < 4; ++r)
#pragma unroll
        for (int c = 0; c < 4; ++c) acc[r][c] = (f32x4){0.f, 0.f, 0.f, 0.f};

    for (int k0 = 0; k0 < Ktot; k0 += 32) {
        uint4 a0 = {0, 0, 0, 0}, a1 = {0, 0, 0, 0};
        if (AF32) {
            if (arow < M) {
                const float* Af = (const float*)A1;
                const size_t p = (size_t)arow * Ktot + k0 + shalf * 16;
                const float4 f0 = *(const float4*)&Af[p + 0];
                const float4 f1 = *(const float4*)&Af[p + 4];
                const float4 f2 = *(const float4*)&Af[p + 8];
                const float4 f3 = *(const float4*)&Af[p + 12];
                union { uint4 v[2]; unsigned short s[16]; } pk;
                pk.s[0] = f2bf(f0.x);  pk.s[1] = f2bf(f0.y);
                pk.s[2] = f2bf(f0.z);  pk.s[3] = f2bf(f0.w);
                pk.s[4] = f2bf(f1.x);  pk.s[5] = f2bf(f1.y);
                pk.s[6] = f2bf(f1.z);  pk.s[7] = f2bf(f1.w);
                pk.s[8] = f2bf(f2.x);  pk.s[9] = f2bf(f2.y);
                pk.s[10] = f2bf(f2.z); pk.s[11] = f2bf(f2.w);
                pk.s[12] = f2bf(f3.x); pk.s[13] = f2bf(f3.y);
                pk.s[14] = f2bf(f3.z); pk.s[15] = f2bf(f3.w);
                a0 = pk.v[0]; a1 = pk.v[1];
            }
        } else {
            const unsigned short* Ap = (const unsigned short*)((k0 < 256) ? A1 : A2);
            const int ka = k0 & 255;
            if (arow < M) {
                const size_t p = (size_t)arow * 256 + ka + shalf * 16;
                a0 = *(const uint4*)&Ap[p];
                a1 = *(const uint4*)&Ap[p + 8];
            }
        }
        const size_t pb = (size_t)(col0 + srow) * Ktot + k0 + shalf * 16;
        const uint4 b0 = *(const uint4*)&Bt[pb];
        const uint4 b1 = *(const uint4*)&Bt[pb + 8];
        __syncthreads();
        *(uint4*)&As[srow][shalf * 16 + 0] = a0;
        *(uint4*)&As[srow][shalf * 16 + 8] = a1;
        *(uint4*)&Bs[srow][shalf * 16 + 0] = b0;
        *(uint4*)&Bs[srow][shalf * 16 + 8] = b1;
        __syncthreads();
        bf16x8 af[4], bf[4];
#pragma unroll
        for (int r = 0; r < 4; ++r)
            af[r] = *(const bf16x8*)&As[wr * 64 + r * 16 + fi][koct * 8];
#pragma unroll
        for (int c = 0; c < 4; ++c)
            bf[c] = *(const bf16x8*)&Bs[wc * 64 + c * 16 + fi][koct * 8];
#pragma unroll
        for (int r = 0; r < 4; ++r)
#pragma unroll
            for (int c = 0; c < 4; ++c)
                acc[r][c] = __builtin_amdgcn_mfma_f32_16x16x32_bf16(af[r], bf[c], acc[r][c], 0, 0, 0);
    }

    float bvv[4], wfc[4];
#pragma unroll
    for (int c = 0; c < 4; ++c) {
        const int col = col0 + wc * 64 + c * 16 + fi;
        bvv[c] = bias[col];
        if (SCORES) wfc[c] = Wfc[col];
    }
#pragma unroll
    for (int r = 0; r < 4; ++r) {
#pragma unroll
        for (int q = 0; q < 4; ++q) {
            const int rr = row0 + wr * 64 + r * 16 + koct * 4 + q;
            float sp = 0.f;
            if (rr < M) {
#pragma unroll
                for (int c = 0; c < 4; ++c) {
                    const int col = col0 + wc * 64 + c * 16 + fi;
                    float v = fmaxf(acc[r][c][q] + bvv[c], 0.f);
                    if (RESID) v += bf2f(resid[(size_t)rr * 256 + col]);
                    out[(size_t)rr * ldo + col] = v;
                    if (SCORES) sp += v * wfc[c];
                }
            }
            if (SCORES) {
                sp += __shfl_xor(sp, 1); sp += __shfl_xor(sp, 2);
                sp += __shfl_xor(sp, 4); sp += __shfl_xor(sp, 8);
                if (fi == 0 && rr < M) atomicAdd(&scores_out[rr], sp);
            }
        }
    }
}

// ---------------------------------------------------------------------------
// fp32 tiled GEMM (64x64 tile, BK=16, 4x4 micro-tile) — used for aux (K=48).
// ---------------------------------------------------------------------------
template <bool RELU>
__launch_bounds__(256)
__global__ void k_gemm(const float* __restrict__ A, const float* __restrict__ A2, int lda, int ksA,
                       const float* __restrict__ W, const float* __restrict__ W2, int ldw, int ksW,
                       const float* __restrict__ bias, float* __restrict__ out, int ldo,
                       int M, int K) {
    __shared__ __align__(16) float As[16][64];
    __shared__ __align__(16) float Ws[16][64];
    const int tid = threadIdx.x;
    const int tx = tid & 15, ty = tid >> 4;
    const int row0 = blockIdx.x * 64, col0 = blockIdx.y * 64;
    const int ar = tid >> 2, ac4 = (tid & 3) << 2;
    const int wk = tid >> 4, wc4 = (tid & 15) << 2;
    const int arow = row0 + ar;

    float acc[4][4] = {{0.f}};

    for (int k0 = 0; k0 < K; k0 += 16) {
        const float* Ap; int ka;
        if (k0 < ksA) { Ap = A; ka = k0; } else { Ap = A2; ka = k0 - ksA; }
        const float* Wp; int kw;
        if (k0 < ksW) { Wp = W; kw = k0; } else { Wp = W2; kw = k0 - ksW; }
        float4 av = make_float4(0.f, 0.f, 0.f, 0.f);
        if (arow < M) av = *(const float4*)&Ap[(size_t)arow * lda + ka + ac4];
        float4 wv = *(const float4*)&Wp[(size_t)(kw + wk) * ldw + col0 + wc4];
        __syncthreads();
        As[ac4 + 0][ar] = av.x; As[ac4 + 1][ar] = av.y;
        As[ac4 + 2][ar] = av.z; As[ac4 + 3][ar] = av.w;
        *(float4*)&Ws[wk][wc4] = wv;
        __syncthreads();
#pragma unroll
        for (int kk = 0; kk < 16; ++kk) {
            const float4 a = *(const float4*)&As[kk][tx << 2];
            const float4 w = *(const float4*)&Ws[kk][ty << 2];
            acc[0][0] += a.x * w.x; acc[0][1] += a.x * w.y; acc[0][2] += a.x * w.z; acc[0][3] += a.x * w.w;
            acc[1][0] += a.y * w.x; acc[1][1] += a.y * w.y; acc[1][2] += a.y * w.z; acc[1][3] += a.y * w.w;
            acc[2][0] += a.z * w.x; acc[2][1] += a.z * w.y; acc[2][2] += a.z * w.z; acc[2][3] += a.z * w.w;
            acc[3][0] += a.w * w.x; acc[3][1] += a.w * w.y; acc[3][2] += a.w * w.z; acc[3][3] += a.w * w.w;
        }
    }
    float4 bv = make_float4(0.f, 0.f, 0.f, 0.f);
    if (bias) bv = *(const float4*)&bias[col0 + (ty << 2)];
#pragma unroll
    for (int i = 0; i < 4; ++i) {
        int row = row0 + (tx << 2) + i;
        if (row >= M) continue;
        float4 v;
        v.x = acc[i][0] + bv.x; v.y = acc[i][1] + bv.y;
        v.z = acc[i][2] + bv.z; v.w = acc[i][3] + bv.w;
        if (RELU) {
            v.x = fmaxf(v.x, 0.f); v.y = fmaxf(v.y, 0.f);
            v.z = fmaxf(v.z, 0.f); v.w = fmaxf(v.w, 0.f);
        }
        *(float4*)&out[(size_t)row * ldo + col0 + (ty << 2)] = v;
    }
}

__global__ void k_primary(const float* __restrict__ scores, const int* __restrict__ pairs,
                          float* __restrict__ out, int p) {
    int i = blockIdx.x * blockDim.x + threadIdx.x;
    if (i < p) {
        int a = pairs[2 * i], b = pairs[2 * i + 1];
        out[i] = sigmoidf_(scores[a] - scores[b]);  // bfc cancels in the diff
    }
}

// attn[n] = sigmoid(hid[n,:] . Wa2 + ba2) — one wave per node (128 feats).
__global__ void k_attn(const float* __restrict__ hid, const float* __restrict__ Wa2,
                       const float* __restrict__ ba2, float* __restrict__ out, int n) {
    int node = blockIdx.x * 4 + (threadIdx.x >> 6);
    int l = threadIdx.x & 63;
    if (node >= n) return;
    const float2 h = *(const float2*)&hid[(size_t)node * 128 + l * 2];
    const float2 w = *(const float2*)&Wa2[l * 2];
    float p = h.x * w.x + h.y * w.y;
    for (int off = 32; off > 0; off >>= 1) p += __shfl_down(p, off);
    if (l == 0) out[node] = sigmoidf_(p + ba2[0]);
}

extern "C" void kernel_launch(void* const* d_in, const int* in_sizes, int n_in,
                              void* d_out, int out_size, void* d_ws, size_t ws_size,
                              hipStream_t stream) {
    const float* x     = (const float*)d_in[0];
    const int*   src   = (const int*)d_in[1];
    const int*   dst   = (const int*)d_in[2];
    const int*   pairs = (const int*)d_in[3];
    const float* raw_w = (const float*)d_in[4];
    const float* Ws1   = (const float*)d_in[5];
    const float* Wn1   = (const float*)d_in[6];
    const float* b1    = (const float*)d_in[7];
    const float* Ws2   = (const float*)d_in[8];
    const float* Wn2   = (const float*)d_in[9];
    const float* b2    = (const float*)d_in[10];
    const float* Wskip = (const float*)d_in[11];
    const float* bskip = (const float*)d_in[12];
    const float* Wg1   = (const float*)d_in[13];
    const float* bg1   = (const float*)d_in[14];
    const float* Wg2   = (const float*)d_in[15];
    const float* bg2   = (const float*)d_in[16];
    const float* Wfc   = (const float*)d_in[17];
    const float* bfc   = (const float*)d_in[18];
    const float* Wa1   = (const float*)d_in[19];
    const float* ba1   = (const float*)d_in[20];
    const float* Wa2   = (const float*)d_in[21];
    const float* ba2   = (const float*)d_in[22];
    (void)bfc;

    const int N = in_sizes[0] / 16;
    const int E = in_sizes[1];
    const int P = in_sizes[3] / 2;

    // ---- workspace layout (~130 MB total) ----
    char* base = (char*)d_ws;
    size_t off = 0;
    auto alloc = [&](size_t bytes) -> char* {
        char* p = base + off;
        off = (off + bytes + 255) & ~(size_t)255;
        return p;
    };
    float* cw      = (float*)alloc(16 * 4);
    float* ns      = (float*)alloc((size_t)N * 4);
    float* scores  = (float*)alloc((size_t)N * 4);
    int*   deg     = (int*)alloc((size_t)2 * N * 4);
    int*   deg_in  = deg;
    int*   deg_out = deg + N;
    int*   row_ptr = (int*)alloc((size_t)(N + 1) * 4);
    int*   part    = (int*)alloc(256 * 4);
    int*   col_idx = (int*)alloc((size_t)E * 4);
    float* X32     = (float*)alloc((size_t)N * 32 * 4);
    float* g16     = (float*)alloc((size_t)N * 16 * 4);
    unsigned short* Wt_emb = (unsigned short*)alloc(256 * 512 * 2);  // [256 cols][512 k]
    unsigned short* Wt_a1  = (unsigned short*)alloc(128 * 256 * 2);  // [128 cols][256 k]
    char*  bigA    = alloc((size_t)N * 256 * 2);   // out1(bf16) -> hid(f32 N*128)
    char*  bigB    = alloc((size_t)N * 256 * 2);   // m2(bf16)  -> a1n+g48 (f32)
    if (off > ws_size) return;  // ws too small: output stays zero (visible failure)

    int* cursor = deg_in;  // deg_in dead after scan1; reuse as scatter cursor

    unsigned short* out1 = (unsigned short*)bigA;
    float*          hid  = (float*)bigA;
    unsigned short* m2   = (unsigned short*)bigB;
    float*          a1n  = (float*)bigB;
    float*          g48  = (float*)(bigB + (size_t)N * 48 * 4);

    float* out         = (float*)d_out;
    float* out_primary = out;
    float* out_aux     = out + P;            // also doubles as emb scratch
    float* out_attn    = out + P + (size_t)N * 256;
    float* emb         = out_aux;

    const int gE   = (E + 255) / 256;
    const int NB   = (N + SCANB - 1) / SCANB;
    const int g16t = (N * 16 + 255) / 256;
    const int g48t = (N * 48 + 255) / 256;
    const int MB   = (N + 63) / 64;
    const int MBT  = (N + 127) / 128;
    const int NW4  = (N + 3) / 4;   // wave-per-node kernels
    const int RNG  = (N + 7) / 8;   // scatter dst-range size
    dim3 blk(256);

    // ---- CSR build ----
    hipMemsetAsync(deg, 0, (size_t)2 * N * 4, stream);
    hipMemsetAsync(scores, 0, (size_t)N * 4, stream);
    k_cw<<<1, 64, 0, stream>>>(raw_w, cw, 16);
    k_hist<<<gE, blk, 0, stream>>>(src, dst, deg_in, deg_out, E);
    k_scan1<<<NB, blk, 0, stream>>>(deg_in, row_ptr, part, N);
    k_scan2<<<1, blk, 0, stream>>>(part, NB);
    k_scan3<<<(N + 255) / 256, blk, 0, stream>>>(row_ptr, cursor, part, N, E);
    k_scatter8<<<1024, blk, 0, stream>>>(src, dst, cursor, col_idx, E, N, RNG);

    // ---- bf16 weight prep for MFMA GEMMs ----
    k_w2bf<<<(256 * 256 + 255) / 256, blk, 0, stream>>>(Ws2, Wt_emb, 256, 256, 512, 0);
    k_w2bf<<<(256 * 256 + 255) / 256, blk, 0, stream>>>(Wn2, Wt_emb, 256, 256, 512, 256);
    k_w2bf<<<(128 * 256 + 255) / 256, blk, 0, stream>>>(Wa1, Wt_a1, 256, 128, 256, 0);

    // ---- node features / layer-1 ----
    k_init<<<g16t, blk, 0, stream>>>(x, cw, deg_out, X32, ns, N);
    k_agg16<<<NW4, blk, 0, stream>>>(x, cw, ns, row_ptr, col_idx, X32, g16, N);
    k_l1<<<dim3(MB, 4), blk, 0, stream>>>(X32, Ws1, Wn1, b1, Wskip, bskip, out1, N);

    // ---- layer 2 (MFMA + fused scores; emb lives in out_aux region) ----
    k_m2<<<NW4, blk, 0, stream>>>(out1, row_ptr, col_idx, m2, N);
    k_gemm_mf<false, true, true><<<dim3(MBT, 2), blk, 0, stream>>>(
        out1, m2, Wt_emb, b2, out1, Wfc, scores, emb, 256, N, 512);

    // ---- heads (consume emb before aux overwrites it) ----
    k_primary<<<(P + 255) / 256, blk, 0, stream>>>(scores, pairs, out_primary, P);
    k_gemm_mf<true, false, false><<<dim3(MBT, 1), blk, 0, stream>>>(
        emb, nullptr, Wt_a1, ba1, nullptr, nullptr, nullptr, hid, 128, N, 256);
    k_attn<<<NW4, blk, 0, stream>>>(hid, Wa2, ba2, out_attn, N);

    // ---- auxiliary criteria-relation branch (writes real aux output last) ----
    k_a1<<<g48t, blk, 0, stream>>>(g16, Wg1, bg1, ns, a1n, N);
    k_agg48<<<NW4, blk, 0, stream>>>(a1n, row_ptr, col_idx, g48, N);
    k_gemm<false><<<dim3(MB, 4), blk, 0, stream>>>(g48, nullptr, 48, 48,
                                                   Wg2, nullptr, 256, 48,
                                                   bg2, out_aux, 256, N, 48);
}